// Round 13
// baseline (1057.484 us; speedup 1.0000x reference)
//
#include <hip/hip_runtime.h>

// MDDNet GNN layer — round 13: node-owned edge blocks, ZERO global atomics.
// R11/R12 algebra: GEMM compute ≈ 44µs, scatter ≈ 350µs; three different
// atomic scatter schemes all ~equal => global atomicAdd is the wall.
// Block b owns nodes [8b, 8b+8): processes their contiguous sorted edge
// range in 64-edge aligned tiles (out-of-range rows -> dump rank), seg-
// accumulates in LDS, then plain-stores 8 finished aggr rows. No memset.
// N=20000, E=320000, D=128, H1=256, H2=512, H3=1024, K3=640.

constexpr int D  = 128;
constexpr int H1 = 256;
constexpr int H2 = 512;
constexpr int H3 = 1024;
constexpr int K3 = D + H2;   // 640

typedef short  bf16x8 __attribute__((ext_vector_type(8)));
typedef ushort u16x8  __attribute__((ext_vector_type(8)));
typedef float  f32x4  __attribute__((ext_vector_type(4)));

__device__ __forceinline__ float leaky(float x) { return x >= 0.f ? x : 0.01f * x; }

__device__ __forceinline__ ushort f2bf(float f) {
    unsigned u = __float_as_uint(f);
    u += 0x7FFFu + ((u >> 16) & 1u);
    return (ushort)(u >> 16);
}

__device__ __forceinline__ int swz(int row, int bytecol) {
    return bytecol ^ ((row & 7) << 4);
}

__device__ __forceinline__ f32x4 mfma16(bf16x8 a, bf16x8 b, f32x4 c) {
    return __builtin_amdgcn_mfma_f32_16x16x32_bf16(a, b, c, 0, 0, 0);
}

__device__ __forceinline__ void gload_lds16(const void* g, void* l) {
    __builtin_amdgcn_global_load_lds(
        (const __attribute__((address_space(1))) void*)g,
        (__attribute__((address_space(3))) void*)l, 16, 0, 0);
}

// ---------------------------------------------------------------------------
// Counting sort by dst. scan also emits a preserved row_start[N+1] prefix.
// ---------------------------------------------------------------------------
__global__ __launch_bounds__(256) void hist_kernel(
    const int* __restrict__ dst, int* __restrict__ cursor, int E)
{
    const int i = blockIdx.x * 256 + threadIdx.x;
    if (i < E) atomicAdd(&cursor[dst[i]], 1);
}

__global__ __launch_bounds__(1024) void scan_kernel(
    int* __restrict__ cursor, int* __restrict__ row_start, int n)
{
    __shared__ int sums[1024];
    const int tid  = threadIdx.x;
    const int base = tid * 20;
    int v[20];
    int s = 0;
    #pragma unroll
    for (int i = 0; i < 20; ++i) {
        const int idx = base + i;
        v[i] = (idx < n) ? cursor[idx] : 0;
        s += v[i];
    }
    sums[tid] = s;
    __syncthreads();
    int acc = s;
    for (int d = 1; d < 1024; d <<= 1) {
        const int t = (tid >= d) ? sums[tid - d] : 0;
        __syncthreads();
        acc += t;
        sums[tid] = acc;
        __syncthreads();
    }
    int run = acc - s;   // exclusive base for this thread
    #pragma unroll
    for (int i = 0; i < 20; ++i) {
        const int idx = base + i;
        if (idx < n) { cursor[idx] = run; row_start[idx] = run; }
        run += v[i];
    }
    if (tid == 1023) row_start[n] = acc;   // acc == total == E
}

__global__ __launch_bounds__(256) void scatter_kernel(
    const int* __restrict__ src, const int* __restrict__ dst,
    int* __restrict__ cursor, int* __restrict__ se, int* __restrict__ de,
    int* __restrict__ pe, int E)
{
    const int i = blockIdx.x * 256 + threadIdx.x;
    if (i < E) {
        const int d   = dst[i];
        const int pos = atomicAdd(&cursor[d], 1);
        se[pos] = src[i];
        de[pos] = d;
        pe[pos] = i;
    }
}

// ---------------------------------------------------------------------------
// gather_t: t[pos] = bf16(x0[se[pos]] * ea[pe[pos]]), pre-swizzled chunks.
// ---------------------------------------------------------------------------
__global__ __launch_bounds__(256) void gather_t(
    const float* __restrict__ x0, const float* __restrict__ ea,
    const int* __restrict__ se, const int* __restrict__ pe,
    ushort* __restrict__ t)
{
    const int gid  = blockIdx.x * 256 + threadIdx.x;
    const int e    = gid >> 4;
    const int slot = gid & 15;
    const int s = se[e];
    const int p = pe[e];
    const float4* xp = (const float4*)(x0 + (size_t)s * D + slot * 8);
    const float4* gp = (const float4*)(ea + (size_t)p * D + slot * 8);
    const float4 xa = xp[0], xb = xp[1];
    const float4 ga = gp[0], gb = gp[1];
    u16x8 u;
    u[0] = f2bf(xa.x * ga.x); u[1] = f2bf(xa.y * ga.y);
    u[2] = f2bf(xa.z * ga.z); u[3] = f2bf(xa.w * ga.w);
    u[4] = f2bf(xb.x * gb.x); u[5] = f2bf(xb.y * gb.y);
    u[6] = f2bf(xb.z * gb.z); u[7] = f2bf(xb.w * gb.w);
    const int slot_w = slot ^ (e & 7);
    *(u16x8*)(t + (size_t)e * D + slot_w * 8) = u;
}

// ---------------------------------------------------------------------------
// Pack fp32 W[K][Nc] into bf16 fragment tile order (doubles as A-frag of W^T).
// ---------------------------------------------------------------------------
__global__ __launch_bounds__(256) void pack_weights(
    const float* __restrict__ W, ushort* __restrict__ Wp, int K, int Nc)
{
    const int KT    = K >> 5;
    const int total = (Nc >> 4) * KT * 64;
    const int idx   = blockIdx.x * 256 + threadIdx.x;
    if (idx >= total) return;
    const int l   = idx & 63;
    const int tt  = idx >> 6;
    const int ks  = tt % KT;
    const int ni  = tt / KT;
    const int col = ni * 16 + (l & 15);
    const int k0  = ks * 32 + (l >> 4) * 8;
    u16x8 u;
    #pragma unroll
    for (int j = 0; j < 8; ++j) u[j] = f2bf(W[(size_t)(k0 + j) * Nc + col]);
    *(u16x8*)(Wp + (size_t)idx * 8) = u;
}

// ---------------------------------------------------------------------------
// Node-owned edge GEMM. Block owns nodes [nlo, nlo+NPB); loops over aligned
// 64-edge tiles covering its sorted edge range. GEMM1 -> swapped GEMM2 ->
// shuffle segment-sum -> heads ds_add into seg[rank][col] (rank = dst-nlo,
// out-of-range rows -> dump rank NPB). Final: plain-store NPB aggr rows.
// 512 threads / 8 waves; LDS ~67KB -> 2 blocks/CU. ZERO global atomics.
// ---------------------------------------------------------------------------
constexpr int TE  = 64;
constexpr int NPB = 8;

__global__ __launch_bounds__(512) void edge_gemm_mfma(
    const ushort* __restrict__ t, const int* __restrict__ de,
    const int* __restrict__ row_start,
    const ushort* __restrict__ W1p, const float* __restrict__ b1,
    const ushort* __restrict__ W2p, const float* __restrict__ b2,
    float* __restrict__ aggr)
{
    __shared__ __align__(16) ushort t_lds[TE * D];      // 16 KB
    __shared__ __align__(16) ushort m1_lds[TE * H1];    // 32 KB
    __shared__ __align__(16) float seg[(NPB + 1) * H2]; // 18.4 KB
    __shared__ int rank_l[TE];

    const int tid  = threadIdx.x;
    const int lane = tid & 63;
    const int w    = tid >> 6;     // 0..7
    const int lr   = lane & 15;
    const int lg   = lane >> 4;

    const int nlo    = blockIdx.x * NPB;
    const int estart = row_start[nlo];
    const int eend   = row_start[nlo + NPB];

    // zero seg accumulator (first in-loop barrier orders it vs first ds_add)
    #pragma unroll
    for (int i = 0; i < (NPB + 1) * H2 / 512; ++i) seg[i * 512 + tid] = 0.f;

    const int tile_lo = estart >> 6;
    const int tile_hi = (eend - 1) >> 6;   // eend>estart always has >=1 tile

    for (int tile = tile_lo; tile <= tile_hi; ++tile) {
        const int e0 = tile * 64;

        // stage t tile (aligned 64-edge window; swizzle parity preserved)
        const ushort* gsrc = t + (size_t)e0 * D;
        #pragma unroll
        for (int i = 0; i < 2; ++i) {
            const int c = (w * 2 + i) * 64 + lane;
            gload_lds16(gsrc + (size_t)c * 8, t_lds + (w * 2 + i) * 512);
        }
        if (tid < TE) {
            const int e = e0 + tid;
            rank_l[tid] = (e >= estart && e < eend) ? (de[e] - nlo) : NPB;
        }
        __syncthreads();   // t_lds + rank_l (+ seg zeros on first iter)

        // ---- GEMM1: m1[64][256] = leaky(t @ W1 + b1)
        {
            f32x4 acc[4][2];
            #pragma unroll
            for (int ntl = 0; ntl < 2; ++ntl) {
                const float b = b1[(w * 2 + ntl) * 16 + lr];
                #pragma unroll
                for (int mt = 0; mt < 4; ++mt) acc[mt][ntl] = (f32x4){b, b, b, b};
            }
            #pragma unroll
            for (int ks = 0; ks < 4; ++ks) {
                bf16x8 af[4];
                #pragma unroll
                for (int mt = 0; mt < 4; ++mt) {
                    const int row = mt * 16 + lr;
                    af[mt] = *(const bf16x8*)((const char*)t_lds + row * 256 +
                                              swz(row, ks * 64 + lg * 16));
                }
                #pragma unroll
                for (int ntl = 0; ntl < 2; ++ntl) {
                    const bf16x8 bf = *(const bf16x8*)(W1p +
                        ((size_t)((w * 2 + ntl) * 4 + ks) * 64 + lane) * 8);
                    #pragma unroll
                    for (int mt = 0; mt < 4; ++mt)
                        acc[mt][ntl] = mfma16(af[mt], bf, acc[mt][ntl]);
                }
            }
            #pragma unroll
            for (int mt = 0; mt < 4; ++mt)
                #pragma unroll
                for (int ntl = 0; ntl < 2; ++ntl)
                    #pragma unroll
                    for (int r = 0; r < 4; ++r) {
                        const int row = mt * 16 + lg * 4 + r;
                        const int col = (w * 2 + ntl) * 16 + lr;
                        *(ushort*)((char*)m1_lds + row * 512 + swz(row, col * 2)) =
                            f2bf(leaky(acc[mt][ntl][r]));
                    }
        }
        __syncthreads();   // m1 ready

        // ---- swapped GEMM2: D[i][e] = (W2^T @ m1^T)[i][e] + b2[i]
        f32x4 acc2[4][4];   // [mt][et]
        #pragma unroll
        for (int mt = 0; mt < 4; ++mt) {
            const float4 bb = *(const float4*)(b2 + (w * 4 + mt) * 16 + lg * 4);
            #pragma unroll
            for (int et = 0; et < 4; ++et)
                acc2[mt][et] = (f32x4){bb.x, bb.y, bb.z, bb.w};
        }
        #pragma unroll
        for (int ks = 0; ks < 8; ++ks) {
            bf16x8 mf[4];
            #pragma unroll
            for (int et = 0; et < 4; ++et) {
                const int e = et * 16 + lr;
                mf[et] = *(const bf16x8*)((const char*)m1_lds + e * 512 +
                                          swz(e, ks * 64 + lg * 16));
            }
            #pragma unroll
            for (int mt = 0; mt < 4; ++mt) {
                const bf16x8 wf = *(const bf16x8*)(W2p +
                    ((size_t)((w * 4 + mt) * 8 + ks) * 64 + lane) * 8);
                #pragma unroll
                for (int et = 0; et < 4; ++et)
                    acc2[mt][et] = mfma16(wf, mf[et], acc2[mt][et]);
            }
        }

        // ---- epilogue: leaky -> width-16 segmented suffix-sum -> head-lane
        //      ds_add into seg[rank][col] (dump rank NPB absorbs masked rows).
        #pragma unroll
        for (int et = 0; et < 4; ++et) {
            const int e   = et * 16 + lr;
            const int rk  = rank_l[e];
            const int rkp = __shfl_up(rk, 1, 16);
            const bool head = (lr == 0) || (rk != rkp);
            bool ok[4];
            #pragma unroll
            for (int s = 0; s < 4; ++s) {
                const int d   = 1 << s;
                const int rk2 = __shfl_down(rk, d, 16);
                ok[s] = (lr + d < 16) && (rk2 == rk);
            }
            #pragma unroll
            for (int mt = 0; mt < 4; ++mt) {
                float v[4];
                #pragma unroll
                for (int r = 0; r < 4; ++r) v[r] = leaky(acc2[mt][et][r]);
                #pragma unroll
                for (int s = 0; s < 4; ++s) {
                    const int d = 1 << s;
                    #pragma unroll
                    for (int r = 0; r < 4; ++r) {
                        const float tt = __shfl_down(v[r], d, 16);
                        if (ok[s]) v[r] += tt;
                    }
                }
                if (head) {
                    float* base = &seg[rk * H2 + (w * 4 + mt) * 16 + lg * 4];
                    #pragma unroll
                    for (int r = 0; r < 4; ++r) atomicAdd(base + r, v[r]);
                }
            }
        }
        __syncthreads();   // seg adds done; t_lds/m1_lds free for next tile
    }

    // ---- final: plain-store NPB finished aggr rows (each node owned once)
    // seg[0..NPB*H2) maps 1:1 onto aggr[nlo*H2 ..), float4-vectorized.
    float* adst = aggr + (size_t)nlo * H2;
    #pragma unroll
    for (int i = 0; i < NPB * H2 / (512 * 4); ++i) {
        const int j = (i * 512 + tid) * 4;
        *(float4*)(adst + j) = *(const float4*)(seg + j);
    }
}

// ---------------------------------------------------------------------------
// h[N][1024] = bf16(leaky(concat(x0, aggr) @ W3 + b3)); 8 waves / 512 thr.
// ---------------------------------------------------------------------------
constexpr int TN = 32;

__global__ __launch_bounds__(512) void node_mlp1_mfma(
    const float* __restrict__ x0, const float* __restrict__ aggr,
    const ushort* __restrict__ W3p, const float* __restrict__ b3,
    ushort* __restrict__ h)
{
    __shared__ __align__(16) ushort a_lds[TN * K3];  // 40 KB
    const int tid  = threadIdx.x;
    const int n0   = blockIdx.x * TN;
    const int ch   = blockIdx.y;
    const int lane = tid & 63;
    const int w    = tid >> 6;
    const int lr   = lane & 15;
    const int lg   = lane >> 4;

    #pragma unroll
    for (int i = 0; i < 5; ++i) {
        const int c    = i * 512 + tid;
        const int row  = c / 80;
        const int slot = c % 80;
        const float* sp = (slot < 16)
            ? x0   + (size_t)(n0 + row) * D  + slot * 8
            : aggr + (size_t)(n0 + row) * H2 + (slot - 16) * 8;
        const float4 va = ((const float4*)sp)[0];
        const float4 vb = ((const float4*)sp)[1];
        u16x8 u;
        u[0] = f2bf(va.x); u[1] = f2bf(va.y); u[2] = f2bf(va.z); u[3] = f2bf(va.w);
        u[4] = f2bf(vb.x); u[5] = f2bf(vb.y); u[6] = f2bf(vb.z); u[7] = f2bf(vb.w);
        *(u16x8*)((char*)a_lds + row * 1280 + swz(row, slot * 16)) = u;
    }
    __syncthreads();

    f32x4 acc[2][4];
    #pragma unroll
    for (int ntl = 0; ntl < 4; ++ntl) {
        const int colg = ch * 512 + (w * 4 + ntl) * 16 + lr;
        const float b = b3[colg];
        #pragma unroll
        for (int mt = 0; mt < 2; ++mt) acc[mt][ntl] = (f32x4){b, b, b, b};
    }
    for (int ks = 0; ks < 20; ++ks) {
        bf16x8 af[2];
        #pragma unroll
        for (int mt = 0; mt < 2; ++mt) {
            const int row = mt * 16 + lr;
            af[mt] = *(const bf16x8*)((const char*)a_lds + row * 1280 +
                                      swz(row, ks * 64 + lg * 16));
        }
        #pragma unroll
        for (int ntl = 0; ntl < 4; ++ntl) {
            const int nt = ch * 32 + w * 4 + ntl;
            const bf16x8 bf = *(const bf16x8*)(W3p +
                ((size_t)(nt * 20 + ks) * 64 + lane) * 8);
            #pragma unroll
            for (int mt = 0; mt < 2; ++mt)
                acc[mt][ntl] = mfma16(af[mt], bf, acc[mt][ntl]);
        }
    }
    #pragma unroll
    for (int mt = 0; mt < 2; ++mt)
        #pragma unroll
        for (int ntl = 0; ntl < 4; ++ntl) {
            const int colg = ch * 512 + (w * 4 + ntl) * 16 + lr;
            #pragma unroll
            for (int r = 0; r < 4; ++r) {
                const int row = n0 + mt * 16 + lg * 4 + r;
                h[(size_t)row * H3 + colg] = f2bf(leaky(acc[mt][ntl][r]));
            }
        }
}

// ---------------------------------------------------------------------------
// out = ((h @ W4 + b4)·BN + x0) / 2
// ---------------------------------------------------------------------------
__global__ __launch_bounds__(256) void node_mlp2_mfma(
    const ushort* __restrict__ h, const float* __restrict__ x0,
    const ushort* __restrict__ W4p, const float* __restrict__ b4,
    const float* __restrict__ gamma, const float* __restrict__ beta,
    const float* __restrict__ mean, const float* __restrict__ var,
    float* __restrict__ out)
{
    const int tid  = threadIdx.x;
    const int n0   = blockIdx.x * TN;
    const int lane = tid & 63;
    const int w    = tid >> 6;
    const int lr   = lane & 15;
    const int lg   = lane >> 4;

    f32x4 acc[2][2];
    #pragma unroll
    for (int ntl = 0; ntl < 2; ++ntl) {
        const float b = b4[(w * 2 + ntl) * 16 + lr];
        #pragma unroll
        for (int mt = 0; mt < 2; ++mt) acc[mt][ntl] = (f32x4){b, b, b, b};
    }
    for (int ks = 0; ks < 32; ++ks) {
        bf16x8 af[2];
        #pragma unroll
        for (int mt = 0; mt < 2; ++mt)
            af[mt] = *(const bf16x8*)(h + (size_t)(n0 + mt * 16 + lr) * H3 +
                                      ks * 32 + lg * 8);
        #pragma unroll
        for (int ntl = 0; ntl < 2; ++ntl) {
            const bf16x8 bf = *(const bf16x8*)(W4p +
                ((size_t)((w * 2 + ntl) * 32 + ks) * 64 + lane) * 8);
            #pragma unroll
            for (int mt = 0; mt < 2; ++mt)
                acc[mt][ntl] = mfma16(af[mt], bf, acc[mt][ntl]);
        }
    }
    #pragma unroll
    for (int ntl = 0; ntl < 2; ++ntl) {
        const int col = (w * 2 + ntl) * 16 + lr;
        const float sc = gamma[col] * rsqrtf(var[col] + 1e-5f);
        const float bo = beta[col] - mean[col] * sc;
        #pragma unroll
        for (int mt = 0; mt < 2; ++mt)
            #pragma unroll
            for (int r = 0; r < 4; ++r) {
                const int row = n0 + mt * 16 + lg * 4 + r;
                const float v = acc[mt][ntl][r] * sc + bo;
                out[(size_t)row * D + col] =
                    0.5f * (v + x0[(size_t)row * D + col]);
            }
    }
}

extern "C" void kernel_launch(void* const* d_in, const int* in_sizes, int n_in,
                              void* d_out, int out_size, void* d_ws, size_t ws_size,
                              hipStream_t stream)
{
    const float* x0    = (const float*)d_in[0];
    const int*   ei    = (const int*)d_in[1];
    const float* ea    = (const float*)d_in[2];
    const float* W1    = (const float*)d_in[3];
    const float* b1    = (const float*)d_in[4];
    const float* W2    = (const float*)d_in[5];
    const float* b2    = (const float*)d_in[6];
    const float* W3    = (const float*)d_in[7];
    const float* b3    = (const float*)d_in[8];
    const float* W4    = (const float*)d_in[9];
    const float* b4    = (const float*)d_in[10];
    const float* gamma = (const float*)d_in[11];
    const float* beta  = (const float*)d_in[12];
    const float* mean  = (const float*)d_in[13];
    const float* var   = (const float*)d_in[14];
    float* out = (float*)d_out;

    const int N = in_sizes[0] / D;   // 20000
    const int E = in_sizes[2] / D;   // 320000
    const int* src = ei;
    const int* dst = ei + E;

    char* ws = (char*)d_ws;
    float*  aggr = (float*)ws;
    ushort* t    = (ushort*)(ws + (size_t)N * H2 * 4);
    ushort* h    = t;   // alias: node_mlp1 writes h AFTER edge_gemm consumed t
    char*   p2   = (char*)(t + (size_t)E * D);
    int* cursor    = (int*)p2;           // N
    int* row_start = cursor + N;         // N+1
    int* se        = row_start + N + 1;  // E
    int* de        = se + E;             // E
    int* pe        = de + E;             // E
    ushort* W1p = (ushort*)(pe + E);
    ushort* W2p = W1p + (size_t)(D  / 32) * (H1 / 16) * 512;
    ushort* W3p = W2p + (size_t)(H1 / 32) * (H2 / 16) * 512;
    ushort* W4p = W3p + (size_t)(K3 / 32) * (H3 / 16) * 512;

    hipMemsetAsync(cursor, 0, (size_t)N * sizeof(int), stream);

    pack_weights<<<(4096  + 255) / 256, 256, 0, stream>>>(W1, W1p, D,  H1);
    pack_weights<<<(16384 + 255) / 256, 256, 0, stream>>>(W2, W2p, H1, H2);
    pack_weights<<<(81920 + 255) / 256, 256, 0, stream>>>(W3, W3p, K3, H3);
    pack_weights<<<(16384 + 255) / 256, 256, 0, stream>>>(W4, W4p, H3, D);

    hist_kernel<<<(E + 255) / 256, 256, 0, stream>>>(dst, cursor, E);
    scan_kernel<<<1, 1024, 0, stream>>>(cursor, row_start, N);
    scatter_kernel<<<(E + 255) / 256, 256, 0, stream>>>(src, dst, cursor,
                                                        se, de, pe, E);

    gather_t<<<E / 16, 256, 0, stream>>>(x0, ea, se, pe, t);
    edge_gemm_mfma<<<N / NPB, 512, 0, stream>>>(t, de, row_start,
                                                W1p, b1, W2p, b2, aggr);

    dim3 g1(N / TN, 2);
    node_mlp1_mfma<<<g1, 512, 0, stream>>>(x0, aggr, W3p, b3, h);
    node_mlp2_mfma<<<N / TN, 256, 0, stream>>>(h, x0, W4p, b4, gamma, beta, mean, var, out);
}

// Round 14
// 994.025 us; speedup vs baseline: 1.0638x; 1.0638x over previous
//
#include <hip/hip_runtime.h>

// MDDNet GNN layer — round 14: R13 (node-owned, zero global atomics) with the
// spill fixed: GEMM2 split into two mt-halves (acc2[2][4], epilogued
// immediately), launch_bounds(512,2) raises VGPR ceiling. R13's VGPR=128 +
// FETCH 596MB was scratch thrash (R4 signature), not the structure.
// N=20000, E=320000, D=128, H1=256, H2=512, H3=1024, K3=640.

constexpr int D  = 128;
constexpr int H1 = 256;
constexpr int H2 = 512;
constexpr int H3 = 1024;
constexpr int K3 = D + H2;   // 640

typedef short  bf16x8 __attribute__((ext_vector_type(8)));
typedef ushort u16x8  __attribute__((ext_vector_type(8)));
typedef float  f32x4  __attribute__((ext_vector_type(4)));

__device__ __forceinline__ float leaky(float x) { return x >= 0.f ? x : 0.01f * x; }

__device__ __forceinline__ ushort f2bf(float f) {
    unsigned u = __float_as_uint(f);
    u += 0x7FFFu + ((u >> 16) & 1u);
    return (ushort)(u >> 16);
}

__device__ __forceinline__ int swz(int row, int bytecol) {
    return bytecol ^ ((row & 7) << 4);
}

__device__ __forceinline__ f32x4 mfma16(bf16x8 a, bf16x8 b, f32x4 c) {
    return __builtin_amdgcn_mfma_f32_16x16x32_bf16(a, b, c, 0, 0, 0);
}

__device__ __forceinline__ void gload_lds16(const void* g, void* l) {
    __builtin_amdgcn_global_load_lds(
        (const __attribute__((address_space(1))) void*)g,
        (__attribute__((address_space(3))) void*)l, 16, 0, 0);
}

// ---------------------------------------------------------------------------
// Counting sort by dst. scan also emits a preserved row_start[N+1] prefix.
// ---------------------------------------------------------------------------
__global__ __launch_bounds__(256) void hist_kernel(
    const int* __restrict__ dst, int* __restrict__ cursor, int E)
{
    const int i = blockIdx.x * 256 + threadIdx.x;
    if (i < E) atomicAdd(&cursor[dst[i]], 1);
}

__global__ __launch_bounds__(1024) void scan_kernel(
    int* __restrict__ cursor, int* __restrict__ row_start, int n)
{
    __shared__ int sums[1024];
    const int tid  = threadIdx.x;
    const int base = tid * 20;
    int v[20];
    int s = 0;
    #pragma unroll
    for (int i = 0; i < 20; ++i) {
        const int idx = base + i;
        v[i] = (idx < n) ? cursor[idx] : 0;
        s += v[i];
    }
    sums[tid] = s;
    __syncthreads();
    int acc = s;
    for (int d = 1; d < 1024; d <<= 1) {
        const int t = (tid >= d) ? sums[tid - d] : 0;
        __syncthreads();
        acc += t;
        sums[tid] = acc;
        __syncthreads();
    }
    int run = acc - s;
    #pragma unroll
    for (int i = 0; i < 20; ++i) {
        const int idx = base + i;
        if (idx < n) { cursor[idx] = run; row_start[idx] = run; }
        run += v[i];
    }
    if (tid == 1023) row_start[n] = acc;
}

__global__ __launch_bounds__(256) void scatter_kernel(
    const int* __restrict__ src, const int* __restrict__ dst,
    int* __restrict__ cursor, int* __restrict__ se, int* __restrict__ de,
    int* __restrict__ pe, int E)
{
    const int i = blockIdx.x * 256 + threadIdx.x;
    if (i < E) {
        const int d   = dst[i];
        const int pos = atomicAdd(&cursor[d], 1);
        se[pos] = src[i];
        de[pos] = d;
        pe[pos] = i;
    }
}

// ---------------------------------------------------------------------------
// gather_t: t[pos] = bf16(x0[se[pos]] * ea[pe[pos]]), pre-swizzled chunks.
// ---------------------------------------------------------------------------
__global__ __launch_bounds__(256) void gather_t(
    const float* __restrict__ x0, const float* __restrict__ ea,
    const int* __restrict__ se, const int* __restrict__ pe,
    ushort* __restrict__ t)
{
    const int gid  = blockIdx.x * 256 + threadIdx.x;
    const int e    = gid >> 4;
    const int slot = gid & 15;
    const int s = se[e];
    const int p = pe[e];
    const float4* xp = (const float4*)(x0 + (size_t)s * D + slot * 8);
    const float4* gp = (const float4*)(ea + (size_t)p * D + slot * 8);
    const float4 xa = xp[0], xb = xp[1];
    const float4 ga = gp[0], gb = gp[1];
    u16x8 u;
    u[0] = f2bf(xa.x * ga.x); u[1] = f2bf(xa.y * ga.y);
    u[2] = f2bf(xa.z * ga.z); u[3] = f2bf(xa.w * ga.w);
    u[4] = f2bf(xb.x * gb.x); u[5] = f2bf(xb.y * gb.y);
    u[6] = f2bf(xb.z * gb.z); u[7] = f2bf(xb.w * gb.w);
    const int slot_w = slot ^ (e & 7);
    *(u16x8*)(t + (size_t)e * D + slot_w * 8) = u;
}

// ---------------------------------------------------------------------------
// Pack fp32 W[K][Nc] into bf16 fragment tile order (doubles as A-frag of W^T).
// ---------------------------------------------------------------------------
__global__ __launch_bounds__(256) void pack_weights(
    const float* __restrict__ W, ushort* __restrict__ Wp, int K, int Nc)
{
    const int KT    = K >> 5;
    const int total = (Nc >> 4) * KT * 64;
    const int idx   = blockIdx.x * 256 + threadIdx.x;
    if (idx >= total) return;
    const int l   = idx & 63;
    const int tt  = idx >> 6;
    const int ks  = tt % KT;
    const int ni  = tt / KT;
    const int col = ni * 16 + (l & 15);
    const int k0  = ks * 32 + (l >> 4) * 8;
    u16x8 u;
    #pragma unroll
    for (int j = 0; j < 8; ++j) u[j] = f2bf(W[(size_t)(k0 + j) * Nc + col]);
    *(u16x8*)(Wp + (size_t)idx * 8) = u;
}

// ---------------------------------------------------------------------------
// Node-owned edge GEMM, zero global atomics, spill-safe.
// Block owns nodes [nlo, nlo+NPB); loops over aligned 64-edge tiles covering
// its sorted edge range. GEMM1 -> GEMM2 in two mt-halves (each epilogued
// immediately: shuffle segment-sum -> head-lane ds_add into seg[rank][col]).
// Final: plain-store NPB aggr rows. 512 thr / 8 waves; LDS ~67KB, 2 blk/CU.
// ---------------------------------------------------------------------------
constexpr int TE  = 64;
constexpr int NPB = 8;

__global__ __launch_bounds__(512, 2) void edge_gemm_mfma(
    const ushort* __restrict__ t, const int* __restrict__ de,
    const int* __restrict__ row_start,
    const ushort* __restrict__ W1p, const float* __restrict__ b1,
    const ushort* __restrict__ W2p, const float* __restrict__ b2,
    float* __restrict__ aggr)
{
    __shared__ __align__(16) ushort t_lds[TE * D];      // 16 KB
    __shared__ __align__(16) ushort m1_lds[TE * H1];    // 32 KB
    __shared__ __align__(16) float seg[(NPB + 1) * H2]; // 18.4 KB
    __shared__ int rank_l[TE];

    const int tid  = threadIdx.x;
    const int lane = tid & 63;
    const int w    = tid >> 6;     // 0..7
    const int lr   = lane & 15;
    const int lg   = lane >> 4;

    const int nlo    = blockIdx.x * NPB;
    const int estart = row_start[nlo];
    const int eend   = row_start[nlo + NPB];

    // zero seg accumulator (ordered vs first ds_add by the in-loop barrier)
    #pragma unroll
    for (int i = 0; i < (NPB + 1) * H2 / 512; ++i) seg[i * 512 + tid] = 0.f;

    const int tile_lo = estart >> 6;
    const int tile_hi = (eend - 1) >> 6;

    for (int tile = tile_lo; tile <= tile_hi; ++tile) {
        const int e0 = tile * 64;

        const ushort* gsrc = t + (size_t)e0 * D;
        #pragma unroll
        for (int i = 0; i < 2; ++i) {
            const int c = (w * 2 + i) * 64 + lane;
            gload_lds16(gsrc + (size_t)c * 8, t_lds + (w * 2 + i) * 512);
        }
        if (tid < TE) {
            const int e = e0 + tid;
            rank_l[tid] = (e >= estart && e < eend) ? (de[e] - nlo) : NPB;
        }
        __syncthreads();   // t_lds + rank_l (+ seg zeros on first iter)

        // ---- GEMM1: m1[64][256] = leaky(t @ W1 + b1)
        {
            f32x4 acc[4][2];
            #pragma unroll
            for (int ntl = 0; ntl < 2; ++ntl) {
                const float b = b1[(w * 2 + ntl) * 16 + lr];
                #pragma unroll
                for (int mt = 0; mt < 4; ++mt) acc[mt][ntl] = (f32x4){b, b, b, b};
            }
            #pragma unroll
            for (int ks = 0; ks < 4; ++ks) {
                bf16x8 af[4];
                #pragma unroll
                for (int mt = 0; mt < 4; ++mt) {
                    const int row = mt * 16 + lr;
                    af[mt] = *(const bf16x8*)((const char*)t_lds + row * 256 +
                                              swz(row, ks * 64 + lg * 16));
                }
                #pragma unroll
                for (int ntl = 0; ntl < 2; ++ntl) {
                    const bf16x8 bf = *(const bf16x8*)(W1p +
                        ((size_t)((w * 2 + ntl) * 4 + ks) * 64 + lane) * 8);
                    #pragma unroll
                    for (int mt = 0; mt < 4; ++mt)
                        acc[mt][ntl] = mfma16(af[mt], bf, acc[mt][ntl]);
                }
            }
            #pragma unroll
            for (int mt = 0; mt < 4; ++mt)
                #pragma unroll
                for (int ntl = 0; ntl < 2; ++ntl)
                    #pragma unroll
                    for (int r = 0; r < 4; ++r) {
                        const int row = mt * 16 + lg * 4 + r;
                        const int col = (w * 2 + ntl) * 16 + lr;
                        *(ushort*)((char*)m1_lds + row * 512 + swz(row, col * 2)) =
                            f2bf(leaky(acc[mt][ntl][r]));
                    }
        }
        __syncthreads();   // m1 ready

        // ---- swapped GEMM2 in two mt-halves (acc2[2][4], epilogued at once)
        #pragma unroll
        for (int half = 0; half < 2; ++half) {
            f32x4 acc2[2][4];   // [m][et]
            #pragma unroll
            for (int m = 0; m < 2; ++m) {
                const int mt = half * 2 + m;
                const float4 bb = *(const float4*)(b2 + (w * 4 + mt) * 16 + lg * 4);
                #pragma unroll
                for (int et = 0; et < 4; ++et)
                    acc2[m][et] = (f32x4){bb.x, bb.y, bb.z, bb.w};
            }
            #pragma unroll
            for (int ks = 0; ks < 8; ++ks) {
                bf16x8 mf[4];
                #pragma unroll
                for (int et = 0; et < 4; ++et) {
                    const int e = et * 16 + lr;
                    mf[et] = *(const bf16x8*)((const char*)m1_lds + e * 512 +
                                              swz(e, ks * 64 + lg * 16));
                }
                #pragma unroll
                for (int m = 0; m < 2; ++m) {
                    const int mt = half * 2 + m;
                    const bf16x8 wf = *(const bf16x8*)(W2p +
                        ((size_t)((w * 4 + mt) * 8 + ks) * 64 + lane) * 8);
                    #pragma unroll
                    for (int et = 0; et < 4; ++et)
                        acc2[m][et] = mfma16(wf, mf[et], acc2[m][et]);
                }
            }
            // epilogue: leaky -> width-16 segmented suffix-sum -> head ds_add
            #pragma unroll
            for (int et = 0; et < 4; ++et) {
                const int e   = et * 16 + lr;
                const int rk  = rank_l[e];
                const int rkp = __shfl_up(rk, 1, 16);
                const bool head = (lr == 0) || (rk != rkp);
                bool ok[4];
                #pragma unroll
                for (int s = 0; s < 4; ++s) {
                    const int d   = 1 << s;
                    const int rk2 = __shfl_down(rk, d, 16);
                    ok[s] = (lr + d < 16) && (rk2 == rk);
                }
                #pragma unroll
                for (int m = 0; m < 2; ++m) {
                    const int mt = half * 2 + m;
                    float v[4];
                    #pragma unroll
                    for (int r = 0; r < 4; ++r) v[r] = leaky(acc2[m][et][r]);
                    #pragma unroll
                    for (int s = 0; s < 4; ++s) {
                        const int d = 1 << s;
                        #pragma unroll
                        for (int r = 0; r < 4; ++r) {
                            const float tt = __shfl_down(v[r], d, 16);
                            if (ok[s]) v[r] += tt;
                        }
                    }
                    if (head) {
                        float* base = &seg[rk * H2 + (w * 4 + mt) * 16 + lg * 4];
                        #pragma unroll
                        for (int r = 0; r < 4; ++r) atomicAdd(base + r, v[r]);
                    }
                }
            }
        }
        __syncthreads();   // seg adds done; t_lds/m1_lds free for next tile
    }

    // ---- final: plain-store NPB finished aggr rows (each node owned once)
    float* adst = aggr + (size_t)nlo * H2;
    #pragma unroll
    for (int i = 0; i < NPB * H2 / (512 * 4); ++i) {
        const int j = (i * 512 + tid) * 4;
        *(float4*)(adst + j) = *(const float4*)(seg + j);
    }
}

// ---------------------------------------------------------------------------
// h[N][1024] = bf16(leaky(concat(x0, aggr) @ W3 + b3)); 8 waves / 512 thr.
// ---------------------------------------------------------------------------
constexpr int TN = 32;

__global__ __launch_bounds__(512) void node_mlp1_mfma(
    const float* __restrict__ x0, const float* __restrict__ aggr,
    const ushort* __restrict__ W3p, const float* __restrict__ b3,
    ushort* __restrict__ h)
{
    __shared__ __align__(16) ushort a_lds[TN * K3];  // 40 KB
    const int tid  = threadIdx.x;
    const int n0   = blockIdx.x * TN;
    const int ch   = blockIdx.y;
    const int lane = tid & 63;
    const int w    = tid >> 6;
    const int lr   = lane & 15;
    const int lg   = lane >> 4;

    #pragma unroll
    for (int i = 0; i < 5; ++i) {
        const int c    = i * 512 + tid;
        const int row  = c / 80;
        const int slot = c % 80;
        const float* sp = (slot < 16)
            ? x0   + (size_t)(n0 + row) * D  + slot * 8
            : aggr + (size_t)(n0 + row) * H2 + (slot - 16) * 8;
        const float4 va = ((const float4*)sp)[0];
        const float4 vb = ((const float4*)sp)[1];
        u16x8 u;
        u[0] = f2bf(va.x); u[1] = f2bf(va.y); u[2] = f2bf(va.z); u[3] = f2bf(va.w);
        u[4] = f2bf(vb.x); u[5] = f2bf(vb.y); u[6] = f2bf(vb.z); u[7] = f2bf(vb.w);
        *(u16x8*)((char*)a_lds + row * 1280 + swz(row, slot * 16)) = u;
    }
    __syncthreads();

    f32x4 acc[2][4];
    #pragma unroll
    for (int ntl = 0; ntl < 4; ++ntl) {
        const int colg = ch * 512 + (w * 4 + ntl) * 16 + lr;
        const float b = b3[colg];
        #pragma unroll
        for (int mt = 0; mt < 2; ++mt) acc[mt][ntl] = (f32x4){b, b, b, b};
    }
    for (int ks = 0; ks < 20; ++ks) {
        bf16x8 af[2];
        #pragma unroll
        for (int mt = 0; mt < 2; ++mt) {
            const int row = mt * 16 + lr;
            af[mt] = *(const bf16x8*)((const char*)a_lds + row * 1280 +
                                      swz(row, ks * 64 + lg * 16));
        }
        #pragma unroll
        for (int ntl = 0; ntl < 4; ++ntl) {
            const int nt = ch * 32 + w * 4 + ntl;
            const bf16x8 bf = *(const bf16x8*)(W3p +
                ((size_t)(nt * 20 + ks) * 64 + lane) * 8);
            #pragma unroll
            for (int mt = 0; mt < 2; ++mt)
                acc[mt][ntl] = mfma16(af[mt], bf, acc[mt][ntl]);
        }
    }
    #pragma unroll
    for (int mt = 0; mt < 2; ++mt)
        #pragma unroll
        for (int ntl = 0; ntl < 4; ++ntl) {
            const int colg = ch * 512 + (w * 4 + ntl) * 16 + lr;
            #pragma unroll
            for (int r = 0; r < 4; ++r) {
                const int row = n0 + mt * 16 + lg * 4 + r;
                h[(size_t)row * H3 + colg] = f2bf(leaky(acc[mt][ntl][r]));
            }
        }
}

// ---------------------------------------------------------------------------
// out = ((h @ W4 + b4)·BN + x0) / 2
// ---------------------------------------------------------------------------
__global__ __launch_bounds__(256) void node_mlp2_mfma(
    const ushort* __restrict__ h, const float* __restrict__ x0,
    const ushort* __restrict__ W4p, const float* __restrict__ b4,
    const float* __restrict__ gamma, const float* __restrict__ beta,
    const float* __restrict__ mean, const float* __restrict__ var,
    float* __restrict__ out)
{
    const int tid  = threadIdx.x;
    const int n0   = blockIdx.x * TN;
    const int lane = tid & 63;
    const int w    = tid >> 6;
    const int lr   = lane & 15;
    const int lg   = lane >> 4;

    f32x4 acc[2][2];
    #pragma unroll
    for (int ntl = 0; ntl < 2; ++ntl) {
        const float b = b4[(w * 2 + ntl) * 16 + lr];
        #pragma unroll
        for (int mt = 0; mt < 2; ++mt) acc[mt][ntl] = (f32x4){b, b, b, b};
    }
    for (int ks = 0; ks < 32; ++ks) {
        bf16x8 af[2];
        #pragma unroll
        for (int mt = 0; mt < 2; ++mt)
            af[mt] = *(const bf16x8*)(h + (size_t)(n0 + mt * 16 + lr) * H3 +
                                      ks * 32 + lg * 8);
        #pragma unroll
        for (int ntl = 0; ntl < 2; ++ntl) {
            const bf16x8 bf = *(const bf16x8*)(W4p +
                ((size_t)((w * 2 + ntl) * 32 + ks) * 64 + lane) * 8);
            #pragma unroll
            for (int mt = 0; mt < 2; ++mt)
                acc[mt][ntl] = mfma16(af[mt], bf, acc[mt][ntl]);
        }
    }
    #pragma unroll
    for (int ntl = 0; ntl < 2; ++ntl) {
        const int col = (w * 2 + ntl) * 16 + lr;
        const float sc = gamma[col] * rsqrtf(var[col] + 1e-5f);
        const float bo = beta[col] - mean[col] * sc;
        #pragma unroll
        for (int mt = 0; mt < 2; ++mt)
            #pragma unroll
            for (int r = 0; r < 4; ++r) {
                const int row = n0 + mt * 16 + lg * 4 + r;
                const float v = acc[mt][ntl][r] * sc + bo;
                out[(size_t)row * D + col] =
                    0.5f * (v + x0[(size_t)row * D + col]);
            }
    }
}

extern "C" void kernel_launch(void* const* d_in, const int* in_sizes, int n_in,
                              void* d_out, int out_size, void* d_ws, size_t ws_size,
                              hipStream_t stream)
{
    const float* x0    = (const float*)d_in[0];
    const int*   ei    = (const int*)d_in[1];
    const float* ea    = (const float*)d_in[2];
    const float* W1    = (const float*)d_in[3];
    const float* b1    = (const float*)d_in[4];
    const float* W2    = (const float*)d_in[5];
    const float* b2    = (const float*)d_in[6];
    const float* W3    = (const float*)d_in[7];
    const float* b3    = (const float*)d_in[8];
    const float* W4    = (const float*)d_in[9];
    const float* b4    = (const float*)d_in[10];
    const float* gamma = (const float*)d_in[11];
    const float* beta  = (const float*)d_in[12];
    const float* mean  = (const float*)d_in[13];
    const float* var   = (const float*)d_in[14];
    float* out = (float*)d_out;

    const int N = in_sizes[0] / D;   // 20000
    const int E = in_sizes[2] / D;   // 320000
    const int* src = ei;
    const int* dst = ei + E;

    char* ws = (char*)d_ws;
    float*  aggr = (float*)ws;
    ushort* t    = (ushort*)(ws + (size_t)N * H2 * 4);
    ushort* h    = t;   // alias: node_mlp1 writes h AFTER edge_gemm consumed t
    char*   p2   = (char*)(t + (size_t)E * D);
    int* cursor    = (int*)p2;           // N
    int* row_start = cursor + N;         // N+1
    int* se        = row_start + N + 1;  // E
    int* de        = se + E;             // E
    int* pe        = de + E;             // E
    ushort* W1p = (ushort*)(pe + E);
    ushort* W2p = W1p + (size_t)(D  / 32) * (H1 / 16) * 512;
    ushort* W3p = W2p + (size_t)(H1 / 32) * (H2 / 16) * 512;
    ushort* W4p = W3p + (size_t)(K3 / 32) * (H3 / 16) * 512;

    hipMemsetAsync(cursor, 0, (size_t)N * sizeof(int), stream);

    pack_weights<<<(4096  + 255) / 256, 256, 0, stream>>>(W1, W1p, D,  H1);
    pack_weights<<<(16384 + 255) / 256, 256, 0, stream>>>(W2, W2p, H1, H2);
    pack_weights<<<(81920 + 255) / 256, 256, 0, stream>>>(W3, W3p, K3, H3);
    pack_weights<<<(16384 + 255) / 256, 256, 0, stream>>>(W4, W4p, H3, D);

    hist_kernel<<<(E + 255) / 256, 256, 0, stream>>>(dst, cursor, E);
    scan_kernel<<<1, 1024, 0, stream>>>(cursor, row_start, N);
    scatter_kernel<<<(E + 255) / 256, 256, 0, stream>>>(src, dst, cursor,
                                                        se, de, pe, E);

    gather_t<<<E / 16, 256, 0, stream>>>(x0, ea, se, pe, t);
    edge_gemm_mfma<<<N / NPB, 512, 0, stream>>>(t, de, row_start,
                                                W1p, b1, W2p, b2, aggr);

    dim3 g1(N / TN, 2);
    node_mlp1_mfma<<<g1, 512, 0, stream>>>(x0, aggr, W3p, b3, h);
    node_mlp2_mfma<<<N / TN, 256, 0, stream>>>(h, x0, W4p, b4, gamma, beta, mean, var, out);
}

// Round 15
// 636.658 us; speedup vs baseline: 1.6610x; 1.5613x over previous
//
#include <hip/hip_runtime.h>

// MDDNet GNN layer — round 15: R10 structure with ZERO global atomics.
// Theory: device-scope f32 atomicAdd executes memory-side (per-XCD L2s are
// non-coherent) at ~16 ops/cyc chip-wide => 12.8M atomics ~ 330µs, invariant
// across R6/R10/R12 scatter schemes. Fix: interior ranks plain-store to aggr
// (sole writer); boundary ranks (0, nd-1) plain-store to bpart[tile][2][512];
// cleanup kernel sums <=3 partials per boundary node. No aggr memset.
// N=20000, E=320000, D=128, H1=256, H2=512, H3=1024, K3=640.

constexpr int D  = 128;
constexpr int H1 = 256;
constexpr int H2 = 512;
constexpr int H3 = 1024;
constexpr int K3 = D + H2;   // 640

typedef short  bf16x8 __attribute__((ext_vector_type(8)));
typedef ushort u16x8  __attribute__((ext_vector_type(8)));
typedef float  f32x4  __attribute__((ext_vector_type(4)));

__device__ __forceinline__ float leaky(float x) { return x >= 0.f ? x : 0.01f * x; }

__device__ __forceinline__ ushort f2bf(float f) {
    unsigned u = __float_as_uint(f);
    u += 0x7FFFu + ((u >> 16) & 1u);
    return (ushort)(u >> 16);
}

__device__ __forceinline__ int swz(int row, int bytecol) {
    return bytecol ^ ((row & 7) << 4);
}

__device__ __forceinline__ f32x4 mfma16(bf16x8 a, bf16x8 b, f32x4 c) {
    return __builtin_amdgcn_mfma_f32_16x16x32_bf16(a, b, c, 0, 0, 0);
}

__device__ __forceinline__ void gload_lds16(const void* g, void* l) {
    __builtin_amdgcn_global_load_lds(
        (const __attribute__((address_space(1))) void*)g,
        (__attribute__((address_space(3))) void*)l, 16, 0, 0);
}

// ---------------------------------------------------------------------------
// Counting sort by dst. scan also emits a preserved row_start[N+1] prefix.
// ---------------------------------------------------------------------------
__global__ __launch_bounds__(256) void hist_kernel(
    const int* __restrict__ dst, int* __restrict__ cursor, int E)
{
    const int i = blockIdx.x * 256 + threadIdx.x;
    if (i < E) atomicAdd(&cursor[dst[i]], 1);
}

__global__ __launch_bounds__(1024) void scan_kernel(
    int* __restrict__ cursor, int* __restrict__ row_start, int n)
{
    __shared__ int sums[1024];
    const int tid  = threadIdx.x;
    const int base = tid * 20;
    int v[20];
    int s = 0;
    #pragma unroll
    for (int i = 0; i < 20; ++i) {
        const int idx = base + i;
        v[i] = (idx < n) ? cursor[idx] : 0;
        s += v[i];
    }
    sums[tid] = s;
    __syncthreads();
    int acc = s;
    for (int d = 1; d < 1024; d <<= 1) {
        const int t = (tid >= d) ? sums[tid - d] : 0;
        __syncthreads();
        acc += t;
        sums[tid] = acc;
        __syncthreads();
    }
    int run = acc - s;
    #pragma unroll
    for (int i = 0; i < 20; ++i) {
        const int idx = base + i;
        if (idx < n) { cursor[idx] = run; row_start[idx] = run; }
        run += v[i];
    }
    if (tid == 1023) row_start[n] = acc;
}

__global__ __launch_bounds__(256) void scatter_kernel(
    const int* __restrict__ src, const int* __restrict__ dst,
    int* __restrict__ cursor, int* __restrict__ se, int* __restrict__ de,
    int* __restrict__ pe, int E)
{
    const int i = blockIdx.x * 256 + threadIdx.x;
    if (i < E) {
        const int d   = dst[i];
        const int pos = atomicAdd(&cursor[d], 1);
        se[pos] = src[i];
        de[pos] = d;
        pe[pos] = i;
    }
}

// ---------------------------------------------------------------------------
// gather_t: t[pos] = bf16(x0[se[pos]] * ea[pe[pos]]), pre-swizzled chunks.
// ---------------------------------------------------------------------------
__global__ __launch_bounds__(256) void gather_t(
    const float* __restrict__ x0, const float* __restrict__ ea,
    const int* __restrict__ se, const int* __restrict__ pe,
    ushort* __restrict__ t)
{
    const int gid  = blockIdx.x * 256 + threadIdx.x;
    const int e    = gid >> 4;
    const int slot = gid & 15;
    const int s = se[e];
    const int p = pe[e];
    const float4* xp = (const float4*)(x0 + (size_t)s * D + slot * 8);
    const float4* gp = (const float4*)(ea + (size_t)p * D + slot * 8);
    const float4 xa = xp[0], xb = xp[1];
    const float4 ga = gp[0], gb = gp[1];
    u16x8 u;
    u[0] = f2bf(xa.x * ga.x); u[1] = f2bf(xa.y * ga.y);
    u[2] = f2bf(xa.z * ga.z); u[3] = f2bf(xa.w * ga.w);
    u[4] = f2bf(xb.x * gb.x); u[5] = f2bf(xb.y * gb.y);
    u[6] = f2bf(xb.z * gb.z); u[7] = f2bf(xb.w * gb.w);
    const int slot_w = slot ^ (e & 7);
    *(u16x8*)(t + (size_t)e * D + slot_w * 8) = u;
}

// ---------------------------------------------------------------------------
// Pack fp32 W[K][Nc] into bf16 fragment tile order.
// ---------------------------------------------------------------------------
__global__ __launch_bounds__(256) void pack_weights(
    const float* __restrict__ W, ushort* __restrict__ Wp, int K, int Nc)
{
    const int KT    = K >> 5;
    const int total = (Nc >> 4) * KT * 64;
    const int idx   = blockIdx.x * 256 + threadIdx.x;
    if (idx >= total) return;
    const int l   = idx & 63;
    const int tt  = idx >> 6;
    const int ks  = tt % KT;
    const int ni  = tt / KT;
    const int col = ni * 16 + (l & 15);
    const int k0  = ks * 32 + (l >> 4) * 8;
    u16x8 u;
    #pragma unroll
    for (int j = 0; j < 8; ++j) u[j] = f2bf(W[(size_t)(k0 + j) * Nc + col]);
    *(u16x8*)(Wp + (size_t)idx * 8) = u;
}

// ---------------------------------------------------------------------------
// Edge GEMM (R10 structure, flush rerouted). TE=64, 512 threads, 8 waves.
// rank prefix -> GEMM1 -> GEMM2 (2x256-col passes) -> run-combined ds_add
// into seg[rank] -> ROUTED PLAIN-STORE flush: interior ranks -> aggr (sole
// writer), rank 0 -> bpart[tile][0], rank nd-1 -> bpart[tile][1].
// ---------------------------------------------------------------------------
constexpr int TE = 64;
constexpr int SEGW = 260;

__global__ __launch_bounds__(512) void edge_gemm_mfma(
    const ushort* __restrict__ t, const int* __restrict__ de,
    const ushort* __restrict__ W1p, const float* __restrict__ b1,
    const ushort* __restrict__ W2p, const float* __restrict__ b2,
    float* __restrict__ aggr, float* __restrict__ bpart)
{
    __shared__ __align__(16) ushort t_lds[TE * D];     // 16 KB
    __shared__ __align__(16) ushort m1_lds[TE * H1];   // 32 KB
    __shared__ float seg[TE * SEGW];                   // 66.5 KB
    __shared__ int didx[TE];
    __shared__ int rank_l[TE];
    __shared__ int seg2dst[TE];
    __shared__ int nd_s;

    const int tid  = threadIdx.x;
    const int e0   = blockIdx.x * TE;
    const int lane = tid & 63;
    const int w    = tid >> 6;
    const int lr   = lane & 15;
    const int lg   = lane >> 4;

    const ushort* gsrc = t + (size_t)e0 * D;
    #pragma unroll
    for (int i = 0; i < 2; ++i) {
        const int c = (w * 2 + i) * 64 + lane;
        gload_lds16(gsrc + (size_t)c * 8, t_lds + (w * 2 + i) * 512);
    }
    if (tid < TE) didx[tid] = de[e0 + tid];
    __syncthreads();

    if (tid < 64) {
        const int flag = (tid > 0 && didx[tid] != didx[tid - 1]) ? 1 : 0;
        int v = flag;
        #pragma unroll
        for (int d = 1; d < 64; d <<= 1) {
            const int x = __shfl_up(v, d);
            if (lane >= d) v += x;
        }
        rank_l[tid] = v;
        seg2dst[v]  = didx[tid];
        if (tid == 63) nd_s = v + 1;
    }

    // ---- GEMM1: m1[64][256] = leaky(t @ W1 + b1)
    {
        f32x4 acc[4][2];
        #pragma unroll
        for (int ntl = 0; ntl < 2; ++ntl) {
            const float b = b1[(w * 2 + ntl) * 16 + lr];
            #pragma unroll
            for (int mt = 0; mt < 4; ++mt) acc[mt][ntl] = (f32x4){b, b, b, b};
        }
        #pragma unroll
        for (int ks = 0; ks < 4; ++ks) {
            bf16x8 af[4];
            #pragma unroll
            for (int mt = 0; mt < 4; ++mt) {
                const int row = mt * 16 + lr;
                af[mt] = *(const bf16x8*)((const char*)t_lds + row * 256 +
                                          swz(row, ks * 64 + lg * 16));
            }
            #pragma unroll
            for (int ntl = 0; ntl < 2; ++ntl) {
                const bf16x8 bf = *(const bf16x8*)(W1p +
                    ((size_t)((w * 2 + ntl) * 4 + ks) * 64 + lane) * 8);
                #pragma unroll
                for (int mt = 0; mt < 4; ++mt)
                    acc[mt][ntl] = mfma16(af[mt], bf, acc[mt][ntl]);
            }
        }
        #pragma unroll
        for (int mt = 0; mt < 4; ++mt)
            #pragma unroll
            for (int ntl = 0; ntl < 2; ++ntl)
                #pragma unroll
                for (int r = 0; r < 4; ++r) {
                    const int row = mt * 16 + lg * 4 + r;
                    const int col = (w * 2 + ntl) * 16 + lr;
                    *(ushort*)((char*)m1_lds + row * 512 + swz(row, col * 2)) =
                        f2bf(leaky(acc[mt][ntl][r]));
                }
    }
    __syncthreads();   // m1 + rank/seg2dst/nd ready

    const int nd = nd_s;
    int rk[4][4];
    #pragma unroll
    for (int mt = 0; mt < 4; ++mt)
        #pragma unroll
        for (int r = 0; r < 4; ++r)
            rk[mt][r] = rank_l[mt * 16 + lg * 4 + r];

    // ---- GEMM2 in two 256-col passes, each reduced via seg then flushed
    #pragma unroll
    for (int p = 0; p < 2; ++p) {
        for (int i = tid; i < nd * SEGW; i += 512) seg[i] = 0.f;
        __syncthreads();

        f32x4 acc[4][2];
        #pragma unroll
        for (int ntl = 0; ntl < 2; ++ntl) {
            const int nt = p * 16 + w * 2 + ntl;
            const float b = b2[nt * 16 + lr];
            #pragma unroll
            for (int mt = 0; mt < 4; ++mt) acc[mt][ntl] = (f32x4){b, b, b, b};
        }
        #pragma unroll
        for (int ks = 0; ks < 8; ++ks) {
            bf16x8 af[4];
            #pragma unroll
            for (int mt = 0; mt < 4; ++mt) {
                const int row = mt * 16 + lr;
                af[mt] = *(const bf16x8*)((const char*)m1_lds + row * 512 +
                                          swz(row, ks * 64 + lg * 16));
            }
            #pragma unroll
            for (int ntl = 0; ntl < 2; ++ntl) {
                const int nt = p * 16 + w * 2 + ntl;
                const bf16x8 bf = *(const bf16x8*)(W2p +
                    ((size_t)(nt * 8 + ks) * 64 + lane) * 8);
                #pragma unroll
                for (int mt = 0; mt < 4; ++mt)
                    acc[mt][ntl] = mfma16(af[mt], bf, acc[mt][ntl]);
            }
        }
        // run-combined ds_add into seg[rank][col_local]
        #pragma unroll
        for (int mt = 0; mt < 4; ++mt)
            #pragma unroll
            for (int ntl = 0; ntl < 2; ++ntl) {
                const int col = (w * 2 + ntl) * 16 + lr;   // 0..255
                float s = leaky(acc[mt][ntl][0]);
                #pragma unroll
                for (int r = 1; r < 4; ++r) {
                    const float v = leaky(acc[mt][ntl][r]);
                    if (rk[mt][r] == rk[mt][r - 1]) {
                        s += v;
                    } else {
                        atomicAdd(&seg[rk[mt][r - 1] * SEGW + col], s);
                        s = v;
                    }
                }
                atomicAdd(&seg[rk[mt][3] * SEGW + col], s);
            }
        __syncthreads();

        // ROUTED flush: all plain stores, zero global atomics.
        {
            const int col = tid & 255;
            for (int s = tid >> 8; s < nd; s += 2) {
                const float val = seg[s * SEGW + col];
                if (s == 0)
                    bpart[(size_t)blockIdx.x * 1024 + p * 256 + col] = val;
                else if (s == nd - 1)
                    bpart[(size_t)blockIdx.x * 1024 + 512 + p * 256 + col] = val;
                else
                    aggr[(size_t)seg2dst[s] * H2 + p * 256 + col] = val;
            }
            if (nd == 1 && (tid >> 8) == 1)
                bpart[(size_t)blockIdx.x * 1024 + 512 + p * 256 + col] = 0.f;
        }
        __syncthreads();
    }
}

// ---------------------------------------------------------------------------
// cleanup: boundary/empty nodes = sum of their tile partials.
// Node n interior (rs0%64!=0 && rs1%64!=0 && t1==t2) was plain-stored by the
// edge kernel; all others written here (exact complement, sole writers).
// ---------------------------------------------------------------------------
__global__ __launch_bounds__(512) void cleanup_kernel(
    const int* __restrict__ row_start, const float* __restrict__ bpart,
    float* __restrict__ aggr)
{
    const int col = threadIdx.x;          // 0..511
    const int n0  = blockIdx.x * 8;
    #pragma unroll
    for (int i = 0; i < 8; ++i) {
        const int n   = n0 + i;
        const int rs0 = row_start[n], rs1 = row_start[n + 1];
        if (rs0 == rs1) { aggr[(size_t)n * H2 + col] = 0.f; continue; }
        const int t1 = rs0 >> 6, t2 = (rs1 - 1) >> 6;
        if ((rs0 & 63) && (rs1 & 63) && t1 == t2) continue;   // interior
        float acc = 0.f;
        for (int t = t1; t <= t2; ++t)
            acc += (rs0 <= t * 64) ? bpart[(size_t)t * 1024 + col]
                                   : bpart[(size_t)t * 1024 + 512 + col];
        aggr[(size_t)n * H2 + col] = acc;
    }
}

// ---------------------------------------------------------------------------
// h[N][1024] = bf16(leaky(concat(x0, aggr) @ W3 + b3)); 8 waves / 512 thr.
// ---------------------------------------------------------------------------
constexpr int TN = 32;

__global__ __launch_bounds__(512) void node_mlp1_mfma(
    const float* __restrict__ x0, const float* __restrict__ aggr,
    const ushort* __restrict__ W3p, const float* __restrict__ b3,
    ushort* __restrict__ h)
{
    __shared__ __align__(16) ushort a_lds[TN * K3];  // 40 KB
    const int tid  = threadIdx.x;
    const int n0   = blockIdx.x * TN;
    const int ch   = blockIdx.y;
    const int lane = tid & 63;
    const int w    = tid >> 6;
    const int lr   = lane & 15;
    const int lg   = lane >> 4;

    #pragma unroll
    for (int i = 0; i < 5; ++i) {
        const int c    = i * 512 + tid;
        const int row  = c / 80;
        const int slot = c % 80;
        const float* sp = (slot < 16)
            ? x0   + (size_t)(n0 + row) * D  + slot * 8
            : aggr + (size_t)(n0 + row) * H2 + (slot - 16) * 8;
        const float4 va = ((const float4*)sp)[0];
        const float4 vb = ((const float4*)sp)[1];
        u16x8 u;
        u[0] = f2bf(va.x); u[1] = f2bf(va.y); u[2] = f2bf(va.z); u[3] = f2bf(va.w);
        u[4] = f2bf(vb.x); u[5] = f2bf(vb.y); u[6] = f2bf(vb.z); u[7] = f2bf(vb.w);
        *(u16x8*)((char*)a_lds + row * 1280 + swz(row, slot * 16)) = u;
    }
    __syncthreads();

    f32x4 acc[2][4];
    #pragma unroll
    for (int ntl = 0; ntl < 4; ++ntl) {
        const int colg = ch * 512 + (w * 4 + ntl) * 16 + lr;
        const float b = b3[colg];
        #pragma unroll
        for (int mt = 0; mt < 2; ++mt) acc[mt][ntl] = (f32x4){b, b, b, b};
    }
    for (int ks = 0; ks < 20; ++ks) {
        bf16x8 af[2];
        #pragma unroll
        for (int mt = 0; mt < 2; ++mt) {
            const int row = mt * 16 + lr;
            af[mt] = *(const bf16x8*)((const char*)a_lds + row * 1280 +
                                      swz(row, ks * 64 + lg * 16));
        }
        #pragma unroll
        for (int ntl = 0; ntl < 4; ++ntl) {
            const int nt = ch * 32 + w * 4 + ntl;
            const bf16x8 bf = *(const bf16x8*)(W3p +
                ((size_t)(nt * 20 + ks) * 64 + lane) * 8);
            #pragma unroll
            for (int mt = 0; mt < 2; ++mt)
                acc[mt][ntl] = mfma16(af[mt], bf, acc[mt][ntl]);
        }
    }
    #pragma unroll
    for (int mt = 0; mt < 2; ++mt)
        #pragma unroll
        for (int ntl = 0; ntl < 4; ++ntl) {
            const int colg = ch * 512 + (w * 4 + ntl) * 16 + lr;
            #pragma unroll
            for (int r = 0; r < 4; ++r) {
                const int row = n0 + mt * 16 + lg * 4 + r;
                h[(size_t)row * H3 + colg] = f2bf(leaky(acc[mt][ntl][r]));
            }
        }
}

// ---------------------------------------------------------------------------
// out = ((h @ W4 + b4)·BN + x0) / 2
// ---------------------------------------------------------------------------
__global__ __launch_bounds__(256) void node_mlp2_mfma(
    const ushort* __restrict__ h, const float* __restrict__ x0,
    const ushort* __restrict__ W4p, const float* __restrict__ b4,
    const float* __restrict__ gamma, const float* __restrict__ beta,
    const float* __restrict__ mean, const float* __restrict__ var,
    float* __restrict__ out)
{
    const int tid  = threadIdx.x;
    const int n0   = blockIdx.x * TN;
    const int lane = tid & 63;
    const int w    = tid >> 6;
    const int lr   = lane & 15;
    const int lg   = lane >> 4;

    f32x4 acc[2][2];
    #pragma unroll
    for (int ntl = 0; ntl < 2; ++ntl) {
        const float b = b4[(w * 2 + ntl) * 16 + lr];
        #pragma unroll
        for (int mt = 0; mt < 2; ++mt) acc[mt][ntl] = (f32x4){b, b, b, b};
    }
    for (int ks = 0; ks < 32; ++ks) {
        bf16x8 af[2];
        #pragma unroll
        for (int mt = 0; mt < 2; ++mt)
            af[mt] = *(const bf16x8*)(h + (size_t)(n0 + mt * 16 + lr) * H3 +
                                      ks * 32 + lg * 8);
        #pragma unroll
        for (int ntl = 0; ntl < 2; ++ntl) {
            const bf16x8 bf = *(const bf16x8*)(W4p +
                ((size_t)((w * 2 + ntl) * 32 + ks) * 64 + lane) * 8);
            #pragma unroll
            for (int mt = 0; mt < 2; ++mt)
                acc[mt][ntl] = mfma16(af[mt], bf, acc[mt][ntl]);
        }
    }
    #pragma unroll
    for (int ntl = 0; ntl < 2; ++ntl) {
        const int col = (w * 2 + ntl) * 16 + lr;
        const float sc = gamma[col] * rsqrtf(var[col] + 1e-5f);
        const float bo = beta[col] - mean[col] * sc;
        #pragma unroll
        for (int mt = 0; mt < 2; ++mt)
            #pragma unroll
            for (int r = 0; r < 4; ++r) {
                const int row = n0 + mt * 16 + lg * 4 + r;
                const float v = acc[mt][ntl][r] * sc + bo;
                out[(size_t)row * D + col] =
                    0.5f * (v + x0[(size_t)row * D + col]);
            }
    }
}

extern "C" void kernel_launch(void* const* d_in, const int* in_sizes, int n_in,
                              void* d_out, int out_size, void* d_ws, size_t ws_size,
                              hipStream_t stream)
{
    const float* x0    = (const float*)d_in[0];
    const int*   ei    = (const int*)d_in[1];
    const float* ea    = (const float*)d_in[2];
    const float* W1    = (const float*)d_in[3];
    const float* b1    = (const float*)d_in[4];
    const float* W2    = (const float*)d_in[5];
    const float* b2    = (const float*)d_in[6];
    const float* W3    = (const float*)d_in[7];
    const float* b3    = (const float*)d_in[8];
    const float* W4    = (const float*)d_in[9];
    const float* b4    = (const float*)d_in[10];
    const float* gamma = (const float*)d_in[11];
    const float* beta  = (const float*)d_in[12];
    const float* mean  = (const float*)d_in[13];
    const float* var   = (const float*)d_in[14];
    float* out = (float*)d_out;

    const int N = in_sizes[0] / D;   // 20000
    const int E = in_sizes[2] / D;   // 320000
    const int* src = ei;
    const int* dst = ei + E;

    char* ws = (char*)d_ws;
    float*  aggr = (float*)ws;                             // 41 MB
    ushort* t    = (ushort*)(ws + (size_t)N * H2 * 4);     // 82 MB
    ushort* h    = t;   // alias: node_mlp1 writes h AFTER edge_gemm consumed t
    char*   p2   = (char*)(t + (size_t)E * D);
    int* cursor    = (int*)p2;           // N
    int* row_start = cursor + N;         // N+1
    int* se        = row_start + N + 1;  // E
    int* de        = se + E;             // E
    int* pe        = de + E;             // E
    ushort* W1p = (ushort*)(pe + E);
    ushort* W2p = W1p + (size_t)(D  / 32) * (H1 / 16) * 512;
    ushort* W3p = W2p + (size_t)(H1 / 32) * (H2 / 16) * 512;
    ushort* W4p = W3p + (size_t)(K3 / 32) * (H3 / 16) * 512;
    float* bpart = (float*)(W4p + (size_t)(H3 / 32) * (D / 16) * 512); // 20.5 MB

    hipMemsetAsync(cursor, 0, (size_t)N * sizeof(int), stream);

    pack_weights<<<(4096  + 255) / 256, 256, 0, stream>>>(W1, W1p, D,  H1);
    pack_weights<<<(16384 + 255) / 256, 256, 0, stream>>>(W2, W2p, H1, H2);
    pack_weights<<<(81920 + 255) / 256, 256, 0, stream>>>(W3, W3p, K3, H3);
    pack_weights<<<(16384 + 255) / 256, 256, 0, stream>>>(W4, W4p, H3, D);

    hist_kernel<<<(E + 255) / 256, 256, 0, stream>>>(dst, cursor, E);
    scan_kernel<<<1, 1024, 0, stream>>>(cursor, row_start, N);
    scatter_kernel<<<(E + 255) / 256, 256, 0, stream>>>(src, dst, cursor,
                                                        se, de, pe, E);

    gather_t<<<E / 16, 256, 0, stream>>>(x0, ea, se, pe, t);
    edge_gemm_mfma<<<E / TE, 512, 0, stream>>>(t, de, W1p, b1, W2p, b2,
                                               aggr, bpart);
    cleanup_kernel<<<N / 8, 512, 0, stream>>>(row_start, bpart, aggr);

    dim3 g1(N / TN, 2);
    node_mlp1_mfma<<<g1, 512, 0, stream>>>(x0, aggr, W3p, b3, h);
    node_mlp2_mfma<<<N / TN, 256, 0, stream>>>(h, x0, W4p, b4, gamma, beta, mean, var, out);
}

// Round 17
// 503.789 us; speedup vs baseline: 2.0991x; 1.2637x over previous
//
#include <hip/hip_runtime.h>

// MDDNet GNN layer — round 17: R16 (deferred reduction) with the compile fix
// (f32x4 ext-vector store instead of float4 struct assignment).
// Edge kernel = pure dense MLP, plain m2[E,512] bf16 stores, no reduction;
// aggregate_kernel streams contiguous dst-sorted rows per node.
// N=20000, E=320000, D=128, H1=256, H2=512, H3=1024, K3=640.

constexpr int D  = 128;
constexpr int H1 = 256;
constexpr int H2 = 512;
constexpr int H3 = 1024;
constexpr int K3 = D + H2;   // 640

typedef short  bf16x8 __attribute__((ext_vector_type(8)));
typedef ushort u16x8  __attribute__((ext_vector_type(8)));
typedef float  f32x4  __attribute__((ext_vector_type(4)));

__device__ __forceinline__ float leaky(float x) { return x >= 0.f ? x : 0.01f * x; }

__device__ __forceinline__ ushort f2bf(float f) {
    unsigned u = __float_as_uint(f);
    u += 0x7FFFu + ((u >> 16) & 1u);
    return (ushort)(u >> 16);
}

__device__ __forceinline__ float bf2f(ushort u) {
    return __uint_as_float(((unsigned)u) << 16);
}

__device__ __forceinline__ int swz(int row, int bytecol) {
    return bytecol ^ ((row & 7) << 4);
}

__device__ __forceinline__ f32x4 mfma16(bf16x8 a, bf16x8 b, f32x4 c) {
    return __builtin_amdgcn_mfma_f32_16x16x32_bf16(a, b, c, 0, 0, 0);
}

__device__ __forceinline__ void gload_lds16(const void* g, void* l) {
    __builtin_amdgcn_global_load_lds(
        (const __attribute__((address_space(1))) void*)g,
        (__attribute__((address_space(3))) void*)l, 16, 0, 0);
}

// ---------------------------------------------------------------------------
// Counting sort by dst. scan emits preserved row_start[N+1].
// ---------------------------------------------------------------------------
__global__ __launch_bounds__(256) void hist_kernel(
    const int* __restrict__ dst, int* __restrict__ cursor, int E)
{
    const int i = blockIdx.x * 256 + threadIdx.x;
    if (i < E) atomicAdd(&cursor[dst[i]], 1);
}

__global__ __launch_bounds__(1024) void scan_kernel(
    int* __restrict__ cursor, int* __restrict__ row_start, int n)
{
    __shared__ int sums[1024];
    const int tid  = threadIdx.x;
    const int base = tid * 20;
    int v[20];
    int s = 0;
    #pragma unroll
    for (int i = 0; i < 20; ++i) {
        const int idx = base + i;
        v[i] = (idx < n) ? cursor[idx] : 0;
        s += v[i];
    }
    sums[tid] = s;
    __syncthreads();
    int acc = s;
    for (int d = 1; d < 1024; d <<= 1) {
        const int t = (tid >= d) ? sums[tid - d] : 0;
        __syncthreads();
        acc += t;
        sums[tid] = acc;
        __syncthreads();
    }
    int run = acc - s;
    #pragma unroll
    for (int i = 0; i < 20; ++i) {
        const int idx = base + i;
        if (idx < n) { cursor[idx] = run; row_start[idx] = run; }
        run += v[i];
    }
    if (tid == 1023) row_start[n] = acc;
}

__global__ __launch_bounds__(256) void scatter_kernel(
    const int* __restrict__ src, const int* __restrict__ dst,
    int* __restrict__ cursor, int* __restrict__ se, int* __restrict__ pe,
    int E)
{
    const int i = blockIdx.x * 256 + threadIdx.x;
    if (i < E) {
        const int d   = dst[i];
        const int pos = atomicAdd(&cursor[d], 1);
        se[pos] = src[i];
        pe[pos] = i;
    }
}

// ---------------------------------------------------------------------------
// gather_t: t[pos] = bf16(x0[se[pos]] * ea[pe[pos]]), pre-swizzled chunks.
// ---------------------------------------------------------------------------
__global__ __launch_bounds__(256) void gather_t(
    const float* __restrict__ x0, const float* __restrict__ ea,
    const int* __restrict__ se, const int* __restrict__ pe,
    ushort* __restrict__ t)
{
    const int gid  = blockIdx.x * 256 + threadIdx.x;
    const int e    = gid >> 4;
    const int slot = gid & 15;
    const int s = se[e];
    const int p = pe[e];
    const float4* xp = (const float4*)(x0 + (size_t)s * D + slot * 8);
    const float4* gp = (const float4*)(ea + (size_t)p * D + slot * 8);
    const float4 xa = xp[0], xb = xp[1];
    const float4 ga = gp[0], gb = gp[1];
    u16x8 u;
    u[0] = f2bf(xa.x * ga.x); u[1] = f2bf(xa.y * ga.y);
    u[2] = f2bf(xa.z * ga.z); u[3] = f2bf(xa.w * ga.w);
    u[4] = f2bf(xb.x * gb.x); u[5] = f2bf(xb.y * gb.y);
    u[6] = f2bf(xb.z * gb.z); u[7] = f2bf(xb.w * gb.w);
    const int slot_w = slot ^ (e & 7);
    *(u16x8*)(t + (size_t)e * D + slot_w * 8) = u;
}

// ---------------------------------------------------------------------------
// Pack fp32 W[K][Nc] into bf16 B-fragment tile order.
// ---------------------------------------------------------------------------
__global__ __launch_bounds__(256) void pack_weights(
    const float* __restrict__ W, ushort* __restrict__ Wp, int K, int Nc)
{
    const int KT    = K >> 5;
    const int total = (Nc >> 4) * KT * 64;
    const int idx   = blockIdx.x * 256 + threadIdx.x;
    if (idx >= total) return;
    const int l   = idx & 63;
    const int tt  = idx >> 6;
    const int ks  = tt % KT;
    const int ni  = tt / KT;
    const int col = ni * 16 + (l & 15);
    const int k0  = ks * 32 + (l >> 4) * 8;
    u16x8 u;
    #pragma unroll
    for (int j = 0; j < 8; ++j) u[j] = f2bf(W[(size_t)(k0 + j) * Nc + col]);
    *(u16x8*)(Wp + (size_t)idx * 8) = u;
}

// ---------------------------------------------------------------------------
// Pure dense edge MLP: stage t tile -> GEMM1 (m1 in LDS) -> GEMM2 ->
// leaky -> bf16 -> PLAIN stores of m2[E][512]. No graph data, no atomics,
// no reduction. TE=64, 512 threads, 8 waves, LDS 48.5KB.
// ---------------------------------------------------------------------------
constexpr int TE = 64;

__global__ __launch_bounds__(512) void edge_mlp_dense(
    const ushort* __restrict__ t,
    const ushort* __restrict__ W1p, const float* __restrict__ b1,
    const ushort* __restrict__ W2p, const float* __restrict__ b2,
    ushort* __restrict__ m2)
{
    __shared__ __align__(16) ushort t_lds[TE * D];     // 16 KB
    __shared__ __align__(16) ushort m1_lds[TE * H1];   // 32 KB

    const int tid  = threadIdx.x;
    const int e0   = blockIdx.x * TE;
    const int lane = tid & 63;
    const int w    = tid >> 6;     // 0..7
    const int lr   = lane & 15;
    const int lg   = lane >> 4;

    // async stage: 1024 x 16B chunks, 2 per thread
    const ushort* gsrc = t + (size_t)e0 * D;
    #pragma unroll
    for (int i = 0; i < 2; ++i) {
        const int c = (w * 2 + i) * 64 + lane;
        gload_lds16(gsrc + (size_t)c * 8, t_lds + (w * 2 + i) * 512);
    }
    __syncthreads();

    // ---- GEMM1: m1[64][256] = leaky(t @ W1 + b1); wave owns ntiles {2w,2w+1}
    {
        f32x4 acc[4][2];
        #pragma unroll
        for (int ntl = 0; ntl < 2; ++ntl) {
            const float b = b1[(w * 2 + ntl) * 16 + lr];
            #pragma unroll
            for (int mt = 0; mt < 4; ++mt) acc[mt][ntl] = (f32x4){b, b, b, b};
        }
        #pragma unroll
        for (int ks = 0; ks < 4; ++ks) {
            bf16x8 af[4];
            #pragma unroll
            for (int mt = 0; mt < 4; ++mt) {
                const int row = mt * 16 + lr;
                af[mt] = *(const bf16x8*)((const char*)t_lds + row * 256 +
                                          swz(row, ks * 64 + lg * 16));
            }
            #pragma unroll
            for (int ntl = 0; ntl < 2; ++ntl) {
                const bf16x8 bf = *(const bf16x8*)(W1p +
                    ((size_t)((w * 2 + ntl) * 4 + ks) * 64 + lane) * 8);
                #pragma unroll
                for (int mt = 0; mt < 4; ++mt)
                    acc[mt][ntl] = mfma16(af[mt], bf, acc[mt][ntl]);
            }
        }
        #pragma unroll
        for (int mt = 0; mt < 4; ++mt)
            #pragma unroll
            for (int ntl = 0; ntl < 2; ++ntl)
                #pragma unroll
                for (int r = 0; r < 4; ++r) {
                    const int row = mt * 16 + lg * 4 + r;
                    const int col = (w * 2 + ntl) * 16 + lr;
                    *(ushort*)((char*)m1_lds + row * 512 + swz(row, col * 2)) =
                        f2bf(leaky(acc[mt][ntl][r]));
                }
    }
    __syncthreads();   // m1 ready

    // ---- GEMM2: m2[64][512] = leaky(m1 @ W2 + b2), two 256-col passes,
    //      plain bf16 stores (writer of each (row,col) is unique).
    #pragma unroll
    for (int p = 0; p < 2; ++p) {
        f32x4 acc[4][2];
        #pragma unroll
        for (int ntl = 0; ntl < 2; ++ntl) {
            const int nt = p * 16 + w * 2 + ntl;
            const float b = b2[nt * 16 + lr];
            #pragma unroll
            for (int mt = 0; mt < 4; ++mt) acc[mt][ntl] = (f32x4){b, b, b, b};
        }
        #pragma unroll
        for (int ks = 0; ks < 8; ++ks) {
            bf16x8 af[4];
            #pragma unroll
            for (int mt = 0; mt < 4; ++mt) {
                const int row = mt * 16 + lr;
                af[mt] = *(const bf16x8*)((const char*)m1_lds + row * 512 +
                                          swz(row, ks * 64 + lg * 16));
            }
            #pragma unroll
            for (int ntl = 0; ntl < 2; ++ntl) {
                const int nt = p * 16 + w * 2 + ntl;
                const bf16x8 bf = *(const bf16x8*)(W2p +
                    ((size_t)(nt * 8 + ks) * 64 + lane) * 8);
                #pragma unroll
                for (int mt = 0; mt < 4; ++mt)
                    acc[mt][ntl] = mfma16(af[mt], bf, acc[mt][ntl]);
            }
        }
        #pragma unroll
        for (int mt = 0; mt < 4; ++mt)
            #pragma unroll
            for (int ntl = 0; ntl < 2; ++ntl) {
                const int col = (p * 16 + w * 2 + ntl) * 16 + lr;
                #pragma unroll
                for (int r = 0; r < 4; ++r) {
                    const int row = e0 + mt * 16 + lg * 4 + r;
                    m2[(size_t)row * H2 + col] = f2bf(leaky(acc[mt][ntl][r]));
                }
            }
    }
}

// ---------------------------------------------------------------------------
// aggregate: wave per node sums its contiguous dst-sorted m2 rows into aggr.
// Register-private accumulation, coalesced 1KB row loads, plain stores.
// Writes every node (zeros for empty) -> no aggr memset needed.
// ---------------------------------------------------------------------------
__global__ __launch_bounds__(512) void aggregate_kernel(
    const ushort* __restrict__ m2, const int* __restrict__ row_start,
    float* __restrict__ aggr)
{
    const int lane = threadIdx.x & 63;
    const int w    = threadIdx.x >> 6;
    const int n    = blockIdx.x * 8 + w;

    const int rs0 = row_start[n], rs1 = row_start[n + 1];
    float acc[8];
    #pragma unroll
    for (int j = 0; j < 8; ++j) acc[j] = 0.f;

    for (int e = rs0; e < rs1; ++e) {
        const u16x8 v = *(const u16x8*)(m2 + (size_t)e * H2 + lane * 8);
        #pragma unroll
        for (int j = 0; j < 8; ++j) acc[j] += bf2f(v[j]);
    }

    float* dstp = aggr + (size_t)n * H2 + lane * 8;
    f32x4 lo = {acc[0], acc[1], acc[2], acc[3]};
    f32x4 hi = {acc[4], acc[5], acc[6], acc[7]};
    *(f32x4*)dstp       = lo;
    *(f32x4*)(dstp + 4) = hi;
}

// ---------------------------------------------------------------------------
// h[N][1024] = bf16(leaky(concat(x0, aggr) @ W3 + b3)); 8 waves / 512 thr.
// ---------------------------------------------------------------------------
constexpr int TN = 32;

__global__ __launch_bounds__(512) void node_mlp1_mfma(
    const float* __restrict__ x0, const float* __restrict__ aggr,
    const ushort* __restrict__ W3p, const float* __restrict__ b3,
    ushort* __restrict__ h)
{
    __shared__ __align__(16) ushort a_lds[TN * K3];  // 40 KB
    const int tid  = threadIdx.x;
    const int n0   = blockIdx.x * TN;
    const int ch   = blockIdx.y;
    const int lane = tid & 63;
    const int w    = tid >> 6;
    const int lr   = lane & 15;
    const int lg   = lane >> 4;

    #pragma unroll
    for (int i = 0; i < 5; ++i) {
        const int c    = i * 512 + tid;
        const int row  = c / 80;
        const int slot = c % 80;
        const float* sp = (slot < 16)
            ? x0   + (size_t)(n0 + row) * D  + slot * 8
            : aggr + (size_t)(n0 + row) * H2 + (slot - 16) * 8;
        const float4 va = ((const float4*)sp)[0];
        const float4 vb = ((const float4*)sp)[1];
        u16x8 u;
        u[0] = f2bf(va.x); u[1] = f2bf(va.y); u[2] = f2bf(va.z); u[3] = f2bf(va.w);
        u[4] = f2bf(vb.x); u[5] = f2bf(vb.y); u[6] = f2bf(vb.z); u[7] = f2bf(vb.w);
        *(u16x8*)((char*)a_lds + row * 1280 + swz(row, slot * 16)) = u;
    }
    __syncthreads();

    f32x4 acc[2][4];
    #pragma unroll
    for (int ntl = 0; ntl < 4; ++ntl) {
        const int colg = ch * 512 + (w * 4 + ntl) * 16 + lr;
        const float b = b3[colg];
        #pragma unroll
        for (int mt = 0; mt < 2; ++mt) acc[mt][ntl] = (f32x4){b, b, b, b};
    }
    for (int ks = 0; ks < 20; ++ks) {
        bf16x8 af[2];
        #pragma unroll
        for (int mt = 0; mt < 2; ++mt) {
            const int row = mt * 16 + lr;
            af[mt] = *(const bf16x8*)((const char*)a_lds + row * 1280 +
                                      swz(row, ks * 64 + lg * 16));
        }
        #pragma unroll
        for (int ntl = 0; ntl < 4; ++ntl) {
            const int nt = ch * 32 + w * 4 + ntl;
            const bf16x8 bf = *(const bf16x8*)(W3p +
                ((size_t)(nt * 20 + ks) * 64 + lane) * 8);
            #pragma unroll
            for (int mt = 0; mt < 2; ++mt)
                acc[mt][ntl] = mfma16(af[mt], bf, acc[mt][ntl]);
        }
    }
    #pragma unroll
    for (int mt = 0; mt < 2; ++mt)
        #pragma unroll
        for (int ntl = 0; ntl < 4; ++ntl) {
            const int colg = ch * 512 + (w * 4 + ntl) * 16 + lr;
            #pragma unroll
            for (int r = 0; r < 4; ++r) {
                const int row = n0 + mt * 16 + lg * 4 + r;
                h[(size_t)row * H3 + colg] = f2bf(leaky(acc[mt][ntl][r]));
            }
        }
}

// ---------------------------------------------------------------------------
// out = ((h @ W4 + b4)·BN + x0) / 2
// ---------------------------------------------------------------------------
__global__ __launch_bounds__(256) void node_mlp2_mfma(
    const ushort* __restrict__ h, const float* __restrict__ x0,
    const ushort* __restrict__ W4p, const float* __restrict__ b4,
    const float* __restrict__ gamma, const float* __restrict__ beta,
    const float* __restrict__ mean, const float* __restrict__ var,
    float* __restrict__ out)
{
    const int tid  = threadIdx.x;
    const int n0   = blockIdx.x * TN;
    const int lane = tid & 63;
    const int w    = tid >> 6;
    const int lr   = lane & 15;
    const int lg   = lane >> 4;

    f32x4 acc[2][2];
    #pragma unroll
    for (int ntl = 0; ntl < 2; ++ntl) {
        const float b = b4[(w * 2 + ntl) * 16 + lr];
        #pragma unroll
        for (int mt = 0; mt < 2; ++mt) acc[mt][ntl] = (f32x4){b, b, b, b};
    }
    for (int ks = 0; ks < 32; ++ks) {
        bf16x8 af[2];
        #pragma unroll
        for (int mt = 0; mt < 2; ++mt)
            af[mt] = *(const bf16x8*)(h + (size_t)(n0 + mt * 16 + lr) * H3 +
                                      ks * 32 + lg * 8);
        #pragma unroll
        for (int ntl = 0; ntl < 2; ++ntl) {
            const bf16x8 bf = *(const bf16x8*)(W4p +
                ((size_t)((w * 2 + ntl) * 32 + ks) * 64 + lane) * 8);
            #pragma unroll
            for (int mt = 0; mt < 2; ++mt)
                acc[mt][ntl] = mfma16(af[mt], bf, acc[mt][ntl]);
        }
    }
    #pragma unroll
    for (int ntl = 0; ntl < 2; ++ntl) {
        const int col = (w * 2 + ntl) * 16 + lr;
        const float sc = gamma[col] * rsqrtf(var[col] + 1e-5f);
        const float bo = beta[col] - mean[col] * sc;
        #pragma unroll
        for (int mt = 0; mt < 2; ++mt)
            #pragma unroll
            for (int r = 0; r < 4; ++r) {
                const int row = n0 + mt * 16 + lg * 4 + r;
                const float v = acc[mt][ntl][r] * sc + bo;
                out[(size_t)row * D + col] =
                    0.5f * (v + x0[(size_t)row * D + col]);
            }
    }
}

extern "C" void kernel_launch(void* const* d_in, const int* in_sizes, int n_in,
                              void* d_out, int out_size, void* d_ws, size_t ws_size,
                              hipStream_t stream)
{
    const float* x0    = (const float*)d_in[0];
    const int*   ei    = (const int*)d_in[1];
    const float* ea    = (const float*)d_in[2];
    const float* W1    = (const float*)d_in[3];
    const float* b1    = (const float*)d_in[4];
    const float* W2    = (const float*)d_in[5];
    const float* b2    = (const float*)d_in[6];
    const float* W3    = (const float*)d_in[7];
    const float* b3    = (const float*)d_in[8];
    const float* W4    = (const float*)d_in[9];
    const float* b4    = (const float*)d_in[10];
    const float* gamma = (const float*)d_in[11];
    const float* beta  = (const float*)d_in[12];
    const float* mean  = (const float*)d_in[13];
    const float* var   = (const float*)d_in[14];
    float* out = (float*)d_out;

    const int N = in_sizes[0] / D;   // 20000
    const int E = in_sizes[2] / D;   // 320000
    const int* src = ei;
    const int* dst = ei + E;

    // workspace (~455 MB):
    //   aggr f32[N*512]   41.0 MB
    //   t    bf16[E*128]  81.9 MB   (h bf16[N*1024]=41MB aliases t)
    //   m2   bf16[E*512] 327.7 MB
    //   sort ints + packed weights ~4.6 MB
    char* ws = (char*)d_ws;
    float*  aggr = (float*)ws;
    ushort* t    = (ushort*)(ws + (size_t)N * H2 * 4);
    ushort* h    = t;   // alias: node_mlp1 writes h AFTER edge kernel consumed t
    ushort* m2   = t + (size_t)E * D;
    char*   p2   = (char*)(m2 + (size_t)E * H2);
    int* cursor    = (int*)p2;           // N
    int* row_start = cursor + N;         // N+1
    int* se        = row_start + N + 1;  // E
    int* pe        = se + E;             // E
    ushort* W1p = (ushort*)(pe + E);
    ushort* W2p = W1p + (size_t)(D  / 32) * (H1 / 16) * 512;
    ushort* W3p = W2p + (size_t)(H1 / 32) * (H2 / 16) * 512;
    ushort* W4p = W3p + (size_t)(K3 / 32) * (H3 / 16) * 512;

    hipMemsetAsync(cursor, 0, (size_t)N * sizeof(int), stream);

    pack_weights<<<(4096  + 255) / 256, 256, 0, stream>>>(W1, W1p, D,  H1);
    pack_weights<<<(16384 + 255) / 256, 256, 0, stream>>>(W2, W2p, H1, H2);
    pack_weights<<<(81920 + 255) / 256, 256, 0, stream>>>(W3, W3p, K3, H3);
    pack_weights<<<(16384 + 255) / 256, 256, 0, stream>>>(W4, W4p, H3, D);

    hist_kernel<<<(E + 255) / 256, 256, 0, stream>>>(dst, cursor, E);
    scan_kernel<<<1, 1024, 0, stream>>>(cursor, row_start, N);
    scatter_kernel<<<(E + 255) / 256, 256, 0, stream>>>(src, dst, cursor,
                                                        se, pe, E);

    gather_t<<<E / 16, 256, 0, stream>>>(x0, ea, se, pe, t);
    edge_mlp_dense<<<E / TE, 512, 0, stream>>>(t, W1p, b1, W2p, b2, m2);
    aggregate_kernel<<<N / 8, 512, 0, stream>>>(m2, row_start, aggr);

    dim3 g1(N / TN, 2);
    node_mlp1_mfma<<<g1, 512, 0, stream>>>(x0, aggr, W3p, b3, h);
    node_mlp2_mfma<<<N / TN, 256, 0, stream>>>(h, x0, W4p, b4, gamma, beta, mean, var, out);
}

// Round 18
// 488.402 us; speedup vs baseline: 2.1652x; 1.0315x over previous
//
#include <hip/hip_runtime.h>

// MDDNet GNN layer — round 18: R17 + coalesced m2 stores (LDS-staged u16x8,
// 16B/lane) + bf16 aggr (numerically identical: node_mlp1 already rounded
// aggr to bf16 during staging). Edge kernel was 179µs at 2.1TB/s due to
// 2B/lane scattered stores.
// N=20000, E=320000, D=128, H1=256, H2=512, H3=1024, K3=640.

constexpr int D  = 128;
constexpr int H1 = 256;
constexpr int H2 = 512;
constexpr int H3 = 1024;
constexpr int K3 = D + H2;   // 640

typedef short  bf16x8 __attribute__((ext_vector_type(8)));
typedef ushort u16x8  __attribute__((ext_vector_type(8)));
typedef float  f32x4  __attribute__((ext_vector_type(4)));

__device__ __forceinline__ float leaky(float x) { return x >= 0.f ? x : 0.01f * x; }

__device__ __forceinline__ ushort f2bf(float f) {
    unsigned u = __float_as_uint(f);
    u += 0x7FFFu + ((u >> 16) & 1u);
    return (ushort)(u >> 16);
}

__device__ __forceinline__ float bf2f(ushort u) {
    return __uint_as_float(((unsigned)u) << 16);
}

__device__ __forceinline__ int swz(int row, int bytecol) {
    return bytecol ^ ((row & 7) << 4);
}

__device__ __forceinline__ f32x4 mfma16(bf16x8 a, bf16x8 b, f32x4 c) {
    return __builtin_amdgcn_mfma_f32_16x16x32_bf16(a, b, c, 0, 0, 0);
}

__device__ __forceinline__ void gload_lds16(const void* g, void* l) {
    __builtin_amdgcn_global_load_lds(
        (const __attribute__((address_space(1))) void*)g,
        (__attribute__((address_space(3))) void*)l, 16, 0, 0);
}

// ---------------------------------------------------------------------------
// Counting sort by dst. scan emits preserved row_start[N+1].
// ---------------------------------------------------------------------------
__global__ __launch_bounds__(256) void hist_kernel(
    const int* __restrict__ dst, int* __restrict__ cursor, int E)
{
    const int i = blockIdx.x * 256 + threadIdx.x;
    if (i < E) atomicAdd(&cursor[dst[i]], 1);
}

__global__ __launch_bounds__(1024) void scan_kernel(
    int* __restrict__ cursor, int* __restrict__ row_start, int n)
{
    __shared__ int sums[1024];
    const int tid  = threadIdx.x;
    const int base = tid * 20;
    int v[20];
    int s = 0;
    #pragma unroll
    for (int i = 0; i < 20; ++i) {
        const int idx = base + i;
        v[i] = (idx < n) ? cursor[idx] : 0;
        s += v[i];
    }
    sums[tid] = s;
    __syncthreads();
    int acc = s;
    for (int d = 1; d < 1024; d <<= 1) {
        const int t = (tid >= d) ? sums[tid - d] : 0;
        __syncthreads();
        acc += t;
        sums[tid] = acc;
        __syncthreads();
    }
    int run = acc - s;
    #pragma unroll
    for (int i = 0; i < 20; ++i) {
        const int idx = base + i;
        if (idx < n) { cursor[idx] = run; row_start[idx] = run; }
        run += v[i];
    }
    if (tid == 1023) row_start[n] = acc;
}

__global__ __launch_bounds__(256) void scatter_kernel(
    const int* __restrict__ src, const int* __restrict__ dst,
    int* __restrict__ cursor, int* __restrict__ se, int* __restrict__ pe,
    int E)
{
    const int i = blockIdx.x * 256 + threadIdx.x;
    if (i < E) {
        const int d   = dst[i];
        const int pos = atomicAdd(&cursor[d], 1);
        se[pos] = src[i];
        pe[pos] = i;
    }
}

// ---------------------------------------------------------------------------
// gather_t: t[pos] = bf16(x0[se[pos]] * ea[pe[pos]]), pre-swizzled chunks.
// ---------------------------------------------------------------------------
__global__ __launch_bounds__(256) void gather_t(
    const float* __restrict__ x0, const float* __restrict__ ea,
    const int* __restrict__ se, const int* __restrict__ pe,
    ushort* __restrict__ t)
{
    const int gid  = blockIdx.x * 256 + threadIdx.x;
    const int e    = gid >> 4;
    const int slot = gid & 15;
    const int s = se[e];
    const int p = pe[e];
    const float4* xp = (const float4*)(x0 + (size_t)s * D + slot * 8);
    const float4* gp = (const float4*)(ea + (size_t)p * D + slot * 8);
    const float4 xa = xp[0], xb = xp[1];
    const float4 ga = gp[0], gb = gp[1];
    u16x8 u;
    u[0] = f2bf(xa.x * ga.x); u[1] = f2bf(xa.y * ga.y);
    u[2] = f2bf(xa.z * ga.z); u[3] = f2bf(xa.w * ga.w);
    u[4] = f2bf(xb.x * gb.x); u[5] = f2bf(xb.y * gb.y);
    u[6] = f2bf(xb.z * gb.z); u[7] = f2bf(xb.w * gb.w);
    const int slot_w = slot ^ (e & 7);
    *(u16x8*)(t + (size_t)e * D + slot_w * 8) = u;
}

// ---------------------------------------------------------------------------
// Pack fp32 W[K][Nc] into bf16 B-fragment tile order.
// ---------------------------------------------------------------------------
__global__ __launch_bounds__(256) void pack_weights(
    const float* __restrict__ W, ushort* __restrict__ Wp, int K, int Nc)
{
    const int KT    = K >> 5;
    const int total = (Nc >> 4) * KT * 64;
    const int idx   = blockIdx.x * 256 + threadIdx.x;
    if (idx >= total) return;
    const int l   = idx & 63;
    const int tt  = idx >> 6;
    const int ks  = tt % KT;
    const int ni  = tt / KT;
    const int col = ni * 16 + (l & 15);
    const int k0  = ks * 32 + (l >> 4) * 8;
    u16x8 u;
    #pragma unroll
    for (int j = 0; j < 8; ++j) u[j] = f2bf(W[(size_t)(k0 + j) * Nc + col]);
    *(u16x8*)(Wp + (size_t)idx * 8) = u;
}

// ---------------------------------------------------------------------------
// Pure dense edge MLP: stage t -> GEMM1 (m1 in LDS) -> GEMM2 (two 256-col
// passes) -> m2 pass staged in LDS -> COALESCED u16x8 stores (16B/lane).
// TE=64, 512 threads, 8 waves, LDS 80.5KB (2 blocks/CU).
// ---------------------------------------------------------------------------
constexpr int TE = 64;

__global__ __launch_bounds__(512) void edge_mlp_dense(
    const ushort* __restrict__ t,
    const ushort* __restrict__ W1p, const float* __restrict__ b1,
    const ushort* __restrict__ W2p, const float* __restrict__ b2,
    ushort* __restrict__ m2)
{
    __shared__ __align__(16) ushort t_lds[TE * D];      // 16 KB
    __shared__ __align__(16) ushort m1_lds[TE * H1];    // 32 KB
    __shared__ __align__(16) ushort m2_lds[TE * 256];   // 32 KB

    const int tid  = threadIdx.x;
    const int e0   = blockIdx.x * TE;
    const int lane = tid & 63;
    const int w    = tid >> 6;     // 0..7
    const int lr   = lane & 15;
    const int lg   = lane >> 4;

    // async stage: 1024 x 16B chunks, 2 per thread
    const ushort* gsrc = t + (size_t)e0 * D;
    #pragma unroll
    for (int i = 0; i < 2; ++i) {
        const int c = (w * 2 + i) * 64 + lane;
        gload_lds16(gsrc + (size_t)c * 8, t_lds + (w * 2 + i) * 512);
    }
    __syncthreads();

    // ---- GEMM1: m1[64][256] = leaky(t @ W1 + b1); wave owns ntiles {2w,2w+1}
    {
        f32x4 acc[4][2];
        #pragma unroll
        for (int ntl = 0; ntl < 2; ++ntl) {
            const float b = b1[(w * 2 + ntl) * 16 + lr];
            #pragma unroll
            for (int mt = 0; mt < 4; ++mt) acc[mt][ntl] = (f32x4){b, b, b, b};
        }
        #pragma unroll
        for (int ks = 0; ks < 4; ++ks) {
            bf16x8 af[4];
            #pragma unroll
            for (int mt = 0; mt < 4; ++mt) {
                const int row = mt * 16 + lr;
                af[mt] = *(const bf16x8*)((const char*)t_lds + row * 256 +
                                          swz(row, ks * 64 + lg * 16));
            }
            #pragma unroll
            for (int ntl = 0; ntl < 2; ++ntl) {
                const bf16x8 bf = *(const bf16x8*)(W1p +
                    ((size_t)((w * 2 + ntl) * 4 + ks) * 64 + lane) * 8);
                #pragma unroll
                for (int mt = 0; mt < 4; ++mt)
                    acc[mt][ntl] = mfma16(af[mt], bf, acc[mt][ntl]);
            }
        }
        #pragma unroll
        for (int mt = 0; mt < 4; ++mt)
            #pragma unroll
            for (int ntl = 0; ntl < 2; ++ntl)
                #pragma unroll
                for (int r = 0; r < 4; ++r) {
                    const int row = mt * 16 + lg * 4 + r;
                    const int col = (w * 2 + ntl) * 16 + lr;
                    *(ushort*)((char*)m1_lds + row * 512 + swz(row, col * 2)) =
                        f2bf(leaky(acc[mt][ntl][r]));
                }
    }
    __syncthreads();   // m1 ready

    // ---- GEMM2: two 256-col passes; each pass staged in m2_lds then
    //      coalesced-stored (u16x8 per lane = full 1KB row lines per wave).
    #pragma unroll
    for (int p = 0; p < 2; ++p) {
        f32x4 acc[4][2];
        #pragma unroll
        for (int ntl = 0; ntl < 2; ++ntl) {
            const int nt = p * 16 + w * 2 + ntl;
            const float b = b2[nt * 16 + lr];
            #pragma unroll
            for (int mt = 0; mt < 4; ++mt) acc[mt][ntl] = (f32x4){b, b, b, b};
        }
        #pragma unroll
        for (int ks = 0; ks < 8; ++ks) {
            bf16x8 af[4];
            #pragma unroll
            for (int mt = 0; mt < 4; ++mt) {
                const int row = mt * 16 + lr;
                af[mt] = *(const bf16x8*)((const char*)m1_lds + row * 512 +
                                          swz(row, ks * 64 + lg * 16));
            }
            #pragma unroll
            for (int ntl = 0; ntl < 2; ++ntl) {
                const int nt = p * 16 + w * 2 + ntl;
                const bf16x8 bf = *(const bf16x8*)(W2p +
                    ((size_t)(nt * 8 + ks) * 64 + lane) * 8);
                #pragma unroll
                for (int mt = 0; mt < 4; ++mt)
                    acc[mt][ntl] = mfma16(af[mt], bf, acc[mt][ntl]);
            }
        }
        // stage pass tile [64][256] into m2_lds (swizzled, like m1 write)
        #pragma unroll
        for (int mt = 0; mt < 4; ++mt)
            #pragma unroll
            for (int ntl = 0; ntl < 2; ++ntl)
                #pragma unroll
                for (int r = 0; r < 4; ++r) {
                    const int row = mt * 16 + lg * 4 + r;
                    const int col = (w * 2 + ntl) * 16 + lr;   // 0..255
                    *(ushort*)((char*)m2_lds + row * 512 + swz(row, col * 2)) =
                        f2bf(leaky(acc[mt][ntl][r]));
                }
        __syncthreads();
        // coalesced global store: 2048 x 16B chunks, 4 per thread
        #pragma unroll
        for (int i = 0; i < 4; ++i) {
            const int c    = i * 512 + tid;
            const int row  = c >> 5;          // 32 chunks per 256-col row
            const int col8 = c & 31;
            const u16x8 v = *(const u16x8*)((const char*)m2_lds + row * 512 +
                                            swz(row, col8 * 16));
            *(u16x8*)(m2 + (size_t)(e0 + row) * H2 + p * 256 + col8 * 8) = v;
        }
        __syncthreads();   // m2_lds free for next pass
    }
}

// ---------------------------------------------------------------------------
// aggregate: wave per node sums its contiguous dst-sorted m2 rows; writes
// aggr in BF16 (node_mlp1 rounded to bf16 anyway -> numerically identical).
// ---------------------------------------------------------------------------
__global__ __launch_bounds__(512) void aggregate_kernel(
    const ushort* __restrict__ m2, const int* __restrict__ row_start,
    ushort* __restrict__ aggrb)
{
    const int lane = threadIdx.x & 63;
    const int w    = threadIdx.x >> 6;
    const int n    = blockIdx.x * 8 + w;

    const int rs0 = row_start[n], rs1 = row_start[n + 1];
    float acc[8];
    #pragma unroll
    for (int j = 0; j < 8; ++j) acc[j] = 0.f;

    for (int e = rs0; e < rs1; ++e) {
        const u16x8 v = *(const u16x8*)(m2 + (size_t)e * H2 + lane * 8);
        #pragma unroll
        for (int j = 0; j < 8; ++j) acc[j] += bf2f(v[j]);
    }

    u16x8 o;
    #pragma unroll
    for (int j = 0; j < 8; ++j) o[j] = f2bf(acc[j]);
    *(u16x8*)(aggrb + (size_t)n * H2 + lane * 8) = o;
}

// ---------------------------------------------------------------------------
// h[N][1024] = bf16(leaky(concat(x0, aggr_bf16) @ W3 + b3)); 8 waves.
// ---------------------------------------------------------------------------
constexpr int TN = 32;

__global__ __launch_bounds__(512) void node_mlp1_mfma(
    const float* __restrict__ x0, const ushort* __restrict__ aggrb,
    const ushort* __restrict__ W3p, const float* __restrict__ b3,
    ushort* __restrict__ h)
{
    __shared__ __align__(16) ushort a_lds[TN * K3];  // 40 KB
    const int tid  = threadIdx.x;
    const int n0   = blockIdx.x * TN;
    const int ch   = blockIdx.y;
    const int lane = tid & 63;
    const int w    = tid >> 6;
    const int lr   = lane & 15;
    const int lg   = lane >> 4;

    #pragma unroll
    for (int i = 0; i < 5; ++i) {
        const int c    = i * 512 + tid;
        const int row  = c / 80;
        const int slot = c % 80;
        u16x8 u;
        if (slot < 16) {
            const float* sp = x0 + (size_t)(n0 + row) * D + slot * 8;
            const float4 va = ((const float4*)sp)[0];
            const float4 vb = ((const float4*)sp)[1];
            u[0] = f2bf(va.x); u[1] = f2bf(va.y); u[2] = f2bf(va.z); u[3] = f2bf(va.w);
            u[4] = f2bf(vb.x); u[5] = f2bf(vb.y); u[6] = f2bf(vb.z); u[7] = f2bf(vb.w);
        } else {
            u = *(const u16x8*)(aggrb + (size_t)(n0 + row) * H2 + (slot - 16) * 8);
        }
        *(u16x8*)((char*)a_lds + row * 1280 + swz(row, slot * 16)) = u;
    }
    __syncthreads();

    f32x4 acc[2][4];
    #pragma unroll
    for (int ntl = 0; ntl < 4; ++ntl) {
        const int colg = ch * 512 + (w * 4 + ntl) * 16 + lr;
        const float b = b3[colg];
        #pragma unroll
        for (int mt = 0; mt < 2; ++mt) acc[mt][ntl] = (f32x4){b, b, b, b};
    }
    for (int ks = 0; ks < 20; ++ks) {
        bf16x8 af[2];
        #pragma unroll
        for (int mt = 0; mt < 2; ++mt) {
            const int row = mt * 16 + lr;
            af[mt] = *(const bf16x8*)((const char*)a_lds + row * 1280 +
                                      swz(row, ks * 64 + lg * 16));
        }
        #pragma unroll
        for (int ntl = 0; ntl < 4; ++ntl) {
            const int nt = ch * 32 + w * 4 + ntl;
            const bf16x8 bf = *(const bf16x8*)(W3p +
                ((size_t)(nt * 20 + ks) * 64 + lane) * 8);
            #pragma unroll
            for (int mt = 0; mt < 2; ++mt)
                acc[mt][ntl] = mfma16(af[mt], bf, acc[mt][ntl]);
        }
    }
    #pragma unroll
    for (int mt = 0; mt < 2; ++mt)
        #pragma unroll
        for (int ntl = 0; ntl < 4; ++ntl) {
            const int colg = ch * 512 + (w * 4 + ntl) * 16 + lr;
            #pragma unroll
            for (int r = 0; r < 4; ++r) {
                const int row = n0 + mt * 16 + lg * 4 + r;
                h[(size_t)row * H3 + colg] = f2bf(leaky(acc[mt][ntl][r]));
            }
        }
}

// ---------------------------------------------------------------------------
// out = ((h @ W4 + b4)·BN + x0) / 2
// ---------------------------------------------------------------------------
__global__ __launch_bounds__(256) void node_mlp2_mfma(
    const ushort* __restrict__ h, const float* __restrict__ x0,
    const ushort* __restrict__ W4p, const float* __restrict__ b4,
    const float* __restrict__ gamma, const float* __restrict__ beta,
    const float* __restrict__ mean, const float* __restrict__ var,
    float* __restrict__ out)
{
    const int tid  = threadIdx.x;
    const int n0   = blockIdx.x * TN;
    const int lane = tid & 63;
    const int w    = tid >> 6;
    const int lr   = lane & 15;
    const int lg   = lane >> 4;

    f32x4 acc[2][2];
    #pragma unroll
    for (int ntl = 0; ntl < 2; ++ntl) {
        const float b = b4[(w * 2 + ntl) * 16 + lr];
        #pragma unroll
        for (int mt = 0; mt < 2; ++mt) acc[mt][ntl] = (f32x4){b, b, b, b};
    }
    for (int ks = 0; ks < 32; ++ks) {
        bf16x8 af[2];
        #pragma unroll
        for (int mt = 0; mt < 2; ++mt)
            af[mt] = *(const bf16x8*)(h + (size_t)(n0 + mt * 16 + lr) * H3 +
                                      ks * 32 + lg * 8);
        #pragma unroll
        for (int ntl = 0; ntl < 2; ++ntl) {
            const bf16x8 bf = *(const bf16x8*)(W4p +
                ((size_t)((w * 2 + ntl) * 32 + ks) * 64 + lane) * 8);
            #pragma unroll
            for (int mt = 0; mt < 2; ++mt)
                acc[mt][ntl] = mfma16(af[mt], bf, acc[mt][ntl]);
        }
    }
    #pragma unroll
    for (int ntl = 0; ntl < 2; ++ntl) {
        const int col = (w * 2 + ntl) * 16 + lr;
        const float sc = gamma[col] * rsqrtf(var[col] + 1e-5f);
        const float bo = beta[col] - mean[col] * sc;
        #pragma unroll
        for (int mt = 0; mt < 2; ++mt)
            #pragma unroll
            for (int r = 0; r < 4; ++r) {
                const int row = n0 + mt * 16 + lg * 4 + r;
                const float v = acc[mt][ntl][r] * sc + bo;
                out[(size_t)row * D + col] =
                    0.5f * (v + x0[(size_t)row * D + col]);
            }
    }
}

extern "C" void kernel_launch(void* const* d_in, const int* in_sizes, int n_in,
                              void* d_out, int out_size, void* d_ws, size_t ws_size,
                              hipStream_t stream)
{
    const float* x0    = (const float*)d_in[0];
    const int*   ei    = (const int*)d_in[1];
    const float* ea    = (const float*)d_in[2];
    const float* W1    = (const float*)d_in[3];
    const float* b1    = (const float*)d_in[4];
    const float* W2    = (const float*)d_in[5];
    const float* b2    = (const float*)d_in[6];
    const float* W3    = (const float*)d_in[7];
    const float* b3    = (const float*)d_in[8];
    const float* W4    = (const float*)d_in[9];
    const float* b4    = (const float*)d_in[10];
    const float* gamma = (const float*)d_in[11];
    const float* beta  = (const float*)d_in[12];
    const float* mean  = (const float*)d_in[13];
    const float* var   = (const float*)d_in[14];
    float* out = (float*)d_out;

    const int N = in_sizes[0] / D;   // 20000
    const int E = in_sizes[2] / D;   // 320000
    const int* src = ei;
    const int* dst = ei + E;

    // workspace (~435 MB):
    //   aggrb bf16[N*512]  20.5 MB
    //   t     bf16[E*128]  81.9 MB   (h bf16[N*1024]=41MB aliases t)
    //   m2    bf16[E*512] 327.7 MB
    //   sort ints + packed weights ~4.6 MB
    char* ws = (char*)d_ws;
    ushort* aggrb = (ushort*)ws;
    ushort* t     = (ushort*)(ws + (size_t)N * H2 * 2);
    ushort* h     = t;   // alias: node_mlp1 writes h AFTER edge kernel consumed t
    ushort* m2    = t + (size_t)E * D;
    char*   p2    = (char*)(m2 + (size_t)E * H2);
    int* cursor    = (int*)p2;           // N
    int* row_start = cursor + N;         // N+1
    int* se        = row_start + N + 1;  // E
    int* pe        = se + E;             // E
    ushort* W1p = (ushort*)(pe + E);
    ushort* W2p = W1p + (size_t)(D  / 32) * (H1 / 16) * 512;
    ushort* W3p = W2p + (size_t)(H1 / 32) * (H2 / 16) * 512;
    ushort* W4p = W3p + (size_t)(K3 / 32) * (H3 / 16) * 512;

    hipMemsetAsync(cursor, 0, (size_t)N * sizeof(int), stream);

    pack_weights<<<(4096  + 255) / 256, 256, 0, stream>>>(W1, W1p, D,  H1);
    pack_weights<<<(16384 + 255) / 256, 256, 0, stream>>>(W2, W2p, H1, H2);
    pack_weights<<<(81920 + 255) / 256, 256, 0, stream>>>(W3, W3p, K3, H3);
    pack_weights<<<(16384 + 255) / 256, 256, 0, stream>>>(W4, W4p, H3, D);

    hist_kernel<<<(E + 255) / 256, 256, 0, stream>>>(dst, cursor, E);
    scan_kernel<<<1, 1024, 0, stream>>>(cursor, row_start, N);
    scatter_kernel<<<(E + 255) / 256, 256, 0, stream>>>(src, dst, cursor,
                                                        se, pe, E);

    gather_t<<<E / 16, 256, 0, stream>>>(x0, ea, se, pe, t);
    edge_mlp_dense<<<E / TE, 512, 0, stream>>>(t, W1p, b1, W2p, b2, m2);
    aggregate_kernel<<<N / 8, 512, 0, stream>>>(m2, row_start, aggrb);

    dim3 g1(N / TN, 2);
    node_mlp1_mfma<<<g1, 512, 0, stream>>>(x0, aggrb, W3p, b3, h);
    node_mlp2_mfma<<<N / TN, 256, 0, stream>>>(h, x0, W4p, b4, gamma, beta, mean, var, out);
}